// Round 13
// baseline (344.714 us; speedup 1.0000x reference)
//
#include <hip/hip_runtime.h>

typedef __attribute__((ext_vector_type(8))) __bf16 bf16x8;
typedef __attribute__((ext_vector_type(4))) __bf16 bf16x4;
typedef __attribute__((ext_vector_type(4))) float f32x4;

#define DEV static __device__ __forceinline__

DEV float fast_rcp(float x) { return __builtin_amdgcn_rcpf(x); }
DEV float sigm(float x) { return fast_rcp(1.f + __expf(-x)); }
DEV float siluf(float x) { return x * sigm(x); }
DEV float softplusf(float x) { return x > 20.f ? x : __logf(1.f + __expf(x)); }

// R3: no in-kernel grid sync. R5/R9/R11: fusion must DELETE work. R6/R7: stream
// W from L2. R8: pair-split scan. R10: LDS-coalesced transposed stores. R12:
// dts via shfl. R13: intermediate tensors S (chunk states) and z (gate) demoted
// to bf16 -- ~60MB less traffic; rounding applied once per value (carry keeps
// fp32 registers, no compounding).

// ---------------- proj (96->192) MFMA GEMM + BN  ||  weight fp32->bf16 convert ----
__global__ __launch_bounds__(256) void k_proj_wcvt(
    const float* __restrict__ x, const float* __restrict__ pw,
    const float* __restrict__ pb, const float* __restrict__ bng,
    const float* __restrict__ bnb, const float* __restrict__ bnm,
    const float* __restrict__ bnv, float* __restrict__ v,
    const float* __restrict__ Win, const float* __restrict__ Wout,
    const float* __restrict__ Wx, __bf16* __restrict__ Wb)
{
  constexpr int SAP = 104;
  __shared__ __bf16 As[64 * SAP];
  __shared__ __bf16 Ws[64 * SAP];
  const int tid = threadIdx.x;
  const int bid = blockIdx.x;

  if (bid >= 294) {            // ---- wcvt part, float4-vectorized ----
    const int idx = ((bid - 294) * 256 + tid) * 4;   // segments all %4==0
    if (idx < 714240) {
      const float* src;
      if (idx < 442368) src = Win + idx;
      else if (idx < 663552) src = Wout + (idx - 442368);
      else src = Wx + (idx - 663552);
      const float4 tv = *(const float4*)src;
      bf16x4 o;
      o[0] = (__bf16)tv.x; o[1] = (__bf16)tv.y;
      o[2] = (__bf16)tv.z; o[3] = (__bf16)tv.w;
      *(bf16x4*)(Wb + idx) = o;
    }
    return;
  }

  const int r0 = (bid % 98) * 64;
  const int col0 = (bid / 98) * 64;
  const int b = r0 / 3136, l0 = r0 % 3136;
  const int lane = tid & 63, wv = tid >> 6;
  const int rh = wv >> 1, ch = wv & 1;
  const int lm = lane & 15, quad = lane >> 4;

#pragma unroll
  for (int it = 0; it < 6; ++it) {
    const int idx = tid + it * 256;
    const int c = idx >> 4, l4 = idx & 15;
    const float4 t = *(const float4*)(x + ((size_t)(b * 96 + c)) * 3136 + l0 + l4 * 4);
    As[(l4 * 4 + 0) * SAP + c] = (__bf16)t.x;
    As[(l4 * 4 + 1) * SAP + c] = (__bf16)t.y;
    As[(l4 * 4 + 2) * SAP + c] = (__bf16)t.z;
    As[(l4 * 4 + 3) * SAP + c] = (__bf16)t.w;
  }
#pragma unroll
  for (int it = 0; it < 6; ++it) {
    const int idx = tid + it * 256;
    const int wr = idx / 24, kc = (idx % 24) * 4;
    const float4 t = *(const float4*)(pw + (size_t)(col0 + wr) * 96 + kc);
    bf16x4 o;
    o[0] = (__bf16)t.x; o[1] = (__bf16)t.y; o[2] = (__bf16)t.z; o[3] = (__bf16)t.w;
    *(bf16x4*)(&Ws[wr * SAP + kc]) = o;
  }
  __syncthreads();

  f32x4 acc[2][2] = {};
#pragma unroll
  for (int ks = 0; ks < 3; ++ks) {
    const int kb = ks * 32 + quad * 8;
    bf16x8 a0 = *(const bf16x8*)(&As[(rh * 32 + lm) * SAP + kb]);
    bf16x8 a1 = *(const bf16x8*)(&As[(rh * 32 + 16 + lm) * SAP + kb]);
    bf16x8 b0 = *(const bf16x8*)(&Ws[(ch * 32 + lm) * SAP + kb]);
    bf16x8 b1 = *(const bf16x8*)(&Ws[(ch * 32 + 16 + lm) * SAP + kb]);
    acc[0][0] = __builtin_amdgcn_mfma_f32_16x16x32_bf16(a0, b0, acc[0][0], 0, 0, 0);
    acc[0][1] = __builtin_amdgcn_mfma_f32_16x16x32_bf16(a0, b1, acc[0][1], 0, 0, 0);
    acc[1][0] = __builtin_amdgcn_mfma_f32_16x16x32_bf16(a1, b0, acc[1][0], 0, 0, 0);
    acc[1][1] = __builtin_amdgcn_mfma_f32_16x16x32_bf16(a1, b1, acc[1][1], 0, 0, 0);
  }

#pragma unroll
  for (int ti = 0; ti < 2; ++ti)
#pragma unroll
    for (int tj = 0; tj < 2; ++tj) {
      const int gcol = col0 + ch * 32 + tj * 16 + lm;
      const float s = rsqrtf(bnv[gcol] + 1e-5f) * bng[gcol];
      const float sh = (pb[gcol] - bnm[gcol]) * s + bnb[gcol];
#pragma unroll
      for (int j = 0; j < 4; ++j) {
        const int grow = r0 + rh * 32 + ti * 16 + quad * 4 + j;
        v[(size_t)grow * 192 + gcol] = acc[ti][tj][j] * s + sh;
      }
    }
}

// ---------------- depthwise causal conv K=4 + silu, 8 outputs/thread -> xiB bf16 ----
__global__ __launch_bounds__(256) void k_conv(
    const float* __restrict__ xz, __bf16* __restrict__ xiB,
    const float* __restrict__ cw, const float* __restrict__ cb,
    int Lseq, int nthreads)
{
  const int idx = blockIdx.x * 256 + threadIdx.x;
  if (idx >= nthreads) return;
  const int e = idx % 384;
  const int seg = idx / 384;
  const int nseg = Lseq / 8;
  const int b = seg / nseg;
  const int l0 = (seg % nseg) * 8;
  const float4 w4 = *(const float4*)(cw + e * 4);
  const float bv = cb[e];
  float xv[11];
#pragma unroll
  for (int k = 0; k < 11; ++k) {
    const int l = l0 - 3 + k;
    xv[k] = (l >= 0) ? xz[(size_t)(b * Lseq + l) * 768 + e] : 0.f;
  }
#pragma unroll
  for (int j = 0; j < 8; ++j) {
    const float a = bv + xv[j] * w4.x + xv[j + 1] * w4.y + xv[j + 2] * w4.z + xv[j + 3] * w4.w;
    xiB[(size_t)(b * Lseq + l0 + j) * 384 + e] = (__bf16)siluf(a);
  }
}

// ---------------- xz GEMM (K=192, N=768): LN(A) @ Win^T + b, streaming W ---------
// x-half (col0<384) -> xz fp32 (conv needs halo fp32); z-half -> zB bf16.
template <int AMODE>
__global__ __launch_bounds__(256, 4) void k_gemm_xz(
    const float* __restrict__ A, const __bf16* __restrict__ W,
    const float* __restrict__ bias, float* __restrict__ O,
    __bf16* __restrict__ zB,
    int M, const float* __restrict__ lng, const float* __restrict__ lnb)
{
  constexpr int SA = 200;
  __shared__ __bf16 As[64 * SA];
  __shared__ float lnS[384];
  const int tid = threadIdx.x;
  const int r0 = blockIdx.x * 64;
  const int col0 = blockIdx.y * 128;
  const int lane = tid & 63, wv = tid >> 6;
  const int rh = wv & 1, ch = wv >> 1;
  const int lm = lane & 15, quad = lane >> 4;

  if (tid < 192) { lnS[tid] = lng[tid]; lnS[192 + tid] = lnb[tid]; }
  __syncthreads();

  // ---- stage A: 4 lanes per row, LN fused, bf16 out ----
  {
    const int row = tid >> 2, part = tid & 3;
    const int gr = min(r0 + row, M - 1);
    const int cbase = part * 48;
    float4 tv[12];
    if constexpr (AMODE == 2) {
#pragma unroll
      for (int j = 0; j < 12; ++j)
        tv[j] = *(const float4*)(A + (size_t)gr * 192 + cbase + j * 4);
    } else {  // maxpool2 of v (B,3136,192); gr is pooled pixel index
      const int bb = gr / 784, l2 = gr % 784;
      const int h2 = l2 / 28, w2 = l2 % 28;
      const float* p0 = A + (size_t)(bb * 3136 + h2 * 112 + w2 * 2) * 192;
#pragma unroll
      for (int j = 0; j < 12; ++j) {
        const int cc = cbase + j * 4;
        const float4 a0 = *(const float4*)(p0 + cc);
        const float4 a1 = *(const float4*)(p0 + 192 + cc);
        const float4 a2 = *(const float4*)(p0 + 56 * 192 + cc);
        const float4 a3 = *(const float4*)(p0 + 57 * 192 + cc);
        tv[j].x = fmaxf(fmaxf(a0.x, a1.x), fmaxf(a2.x, a3.x));
        tv[j].y = fmaxf(fmaxf(a0.y, a1.y), fmaxf(a2.y, a3.y));
        tv[j].z = fmaxf(fmaxf(a0.z, a1.z), fmaxf(a2.z, a3.z));
        tv[j].w = fmaxf(fmaxf(a0.w, a1.w), fmaxf(a2.w, a3.w));
      }
    }
    float s = 0.f, sq = 0.f;
#pragma unroll
    for (int j = 0; j < 12; ++j) {
      s += tv[j].x + tv[j].y + tv[j].z + tv[j].w;
      sq += tv[j].x * tv[j].x + tv[j].y * tv[j].y + tv[j].z * tv[j].z + tv[j].w * tv[j].w;
    }
    s += __shfl_xor(s, 1); s += __shfl_xor(s, 2);
    sq += __shfl_xor(sq, 1); sq += __shfl_xor(sq, 2);
    const float mean = s * (1.f / 192.f);
    const float rstd = rsqrtf(sq * (1.f / 192.f) - mean * mean + 1e-5f);
#pragma unroll
    for (int j = 0; j < 12; ++j) {
      const int c = cbase + j * 4;
      bf16x4 o;
      o[0] = (__bf16)((tv[j].x - mean) * rstd * lnS[c + 0] + lnS[192 + c + 0]);
      o[1] = (__bf16)((tv[j].y - mean) * rstd * lnS[c + 1] + lnS[192 + c + 1]);
      o[2] = (__bf16)((tv[j].z - mean) * rstd * lnS[c + 2] + lnS[192 + c + 2]);
      o[3] = (__bf16)((tv[j].w - mean) * rstd * lnS[c + 3] + lnS[192 + c + 3]);
      *(bf16x4*)(&As[row * SA + c]) = o;
    }
  }
  __syncthreads();

  // ---- MFMA, B streamed from global ----
  f32x4 acc[2][4] = {};
#pragma unroll
  for (int ks = 0; ks < 6; ++ks) {
    const int kb = ks * 32 + quad * 8;
    bf16x8 a0 = *(const bf16x8*)(&As[(rh * 32 + lm) * SA + kb]);
    bf16x8 a1 = *(const bf16x8*)(&As[(rh * 32 + 16 + lm) * SA + kb]);
#pragma unroll
    for (int tj = 0; tj < 4; ++tj) {
      const int gw = col0 + ch * 64 + tj * 16 + lm;
      bf16x8 bfr = *(const bf16x8*)(W + (size_t)gw * 192 + kb);
      acc[0][tj] = __builtin_amdgcn_mfma_f32_16x16x32_bf16(a0, bfr, acc[0][tj], 0, 0, 0);
      acc[1][tj] = __builtin_amdgcn_mfma_f32_16x16x32_bf16(a1, bfr, acc[1][tj], 0, 0, 0);
    }
  }

  // ---- epilogue: x-half -> xz fp32; z-half -> zB bf16 ----
#pragma unroll
  for (int ti = 0; ti < 2; ++ti)
#pragma unroll
    for (int tj = 0; tj < 4; ++tj) {
      const int gcol = col0 + ch * 64 + tj * 16 + lm;
      const float bv = bias[gcol];
#pragma unroll
      for (int j = 0; j < 4; ++j) {
        const int rowt = rh * 32 + ti * 16 + quad * 4 + j;
        const int grow = r0 + rowt;
        if (grow < M) {
          const float val = acc[ti][tj][j] + bv;
          if (col0 < 384) O[(size_t)grow * 768 + gcol] = val;
          else zB[(size_t)grow * 384 + (gcol - 384)] = (__bf16)val;
        }
      }
    }
}

// ------- streaming-W small-N GEMM, 16-row x 64-col blocks, A-only LDS ----------
constexpr int EPI_G2 = 1, EPI_RES = 2, EPI_RES_SKIP = 3, EPI_OUT2 = 4;

template <int EPI>
__global__ __launch_bounds__(256) void k_gemm_s(
    const __bf16* __restrict__ Ab, const __bf16* __restrict__ W,
    const float* __restrict__ bias, float* __restrict__ O,
    int M, int K, int Nvalid,
    float* __restrict__ dtlbuf, float* __restrict__ bcbuf,
    float* __restrict__ oflt)
{
  constexpr int SA = 200;
  __shared__ __align__(16) char smem[16 * SA * 2];   // As (6400B) / tS (4224B)
  __bf16* As = (__bf16*)smem;
  __shared__ float dtlS[(EPI == EPI_G2) ? 16 * 12 : 1];
  const int tid = threadIdx.x;
  const int r0 = blockIdx.x * 16;
  const int col0 = blockIdx.y * 64;
  const int lane = tid & 63, wv = tid >> 6;
  const int ch = wv;
  const int lm = lane & 15, quad = lane >> 4;

  f32x4 acc = {};
  const int nkp = K / 192;
  for (int kp = 0; kp < nkp; ++kp) {
    if (kp) __syncthreads();
    {
      const int idx = tid;                 // 0..255
      const int row = idx / 24, kc = (idx % 24) * 8;
      const int gr = min(r0 + row, M - 1);
      if (row < 16)
        *(bf16x8*)(&As[row * SA + kc]) =
            *(const bf16x8*)(Ab + (size_t)gr * K + kp * 192 + kc);
      const int idx2 = tid + 256;
      if (idx2 < 384) {
        const int row2 = idx2 / 24, kc2 = (idx2 % 24) * 8;
        const int gr2 = min(r0 + row2, M - 1);
        *(bf16x8*)(&As[row2 * SA + kc2]) =
            *(const bf16x8*)(Ab + (size_t)gr2 * K + kp * 192 + kc2);
      }
    }
    __syncthreads();
#pragma unroll
    for (int ks = 0; ks < 6; ++ks) {
      const int kb = ks * 32 + quad * 8;
      bf16x8 a0 = *(const bf16x8*)(&As[lm * SA + kb]);
      const int gw = min(col0 + ch * 16 + lm, Nvalid - 1);  // clamp: cols >= Nvalid discarded
      bf16x8 bfr = *(const bf16x8*)(W + (size_t)gw * K + kp * 192 + kb);
      acc = __builtin_amdgcn_mfma_f32_16x16x32_bf16(a0, bfr, acc, 0, 0, 0);
    }
  }

  // ---- epilogue ----
  const int colt = ch * 16 + lm;
  if constexpr (EPI == EPI_G2) {
#pragma unroll
    for (int j = 0; j < 4; ++j) {
      const int rowt = quad * 4 + j;
      const int grow = r0 + rowt;
      const float val = acc[j];
      if (colt < 12) dtlS[rowt * 12 + colt] = val;
      else if (colt < 44 && grow < M)
        bcbuf[(size_t)grow * 32 + (colt - 12)] = val;
    }
    __syncthreads();
    if (tid < 192) {
      const int grow = r0 + tid / 12;
      if (grow < M) dtlbuf[(size_t)grow * 12 + tid % 12] = dtlS[tid];
    }
  } else {
    const int gcol = col0 + colt;
    const float bv = bias[gcol];
    float nv4[4];
#pragma unroll
    for (int j = 0; j < 4; ++j) {
      const int rowt = quad * 4 + j;
      const int grow = r0 + rowt;      // grid = M/16 exactly -> always < M
      const float val = acc[j] + bv;
      if constexpr (EPI == EPI_RES) {
        O[(size_t)grow * 192 + gcol] += val;
      } else if constexpr (EPI == EPI_RES_SKIP) {
        const float nvv = O[(size_t)grow * 192 + gcol] + val;
        O[(size_t)grow * 192 + gcol] = nvv;
        nv4[j] = nvv;
      } else {  // EPI_OUT2
        nv4[j] = val;
      }
    }
    if constexpr (EPI == EPI_RES_SKIP || EPI == EPI_OUT2) {
      float* tS = (float*)smem;           // [16][66] fp32 overlaying As
      __syncthreads();                    // all As reads done
#pragma unroll
      for (int j = 0; j < 4; ++j)
        tS[(quad * 4 + j) * 66 + colt] = nv4[j];
      __syncthreads();
      constexpr int Lpix = (EPI == EPI_RES_SKIP) ? 3136 : 784;
      constexpr int strideB = (EPI == EPI_RES_SKIP) ? 602112 : 150528;
      const int c2 = tid >> 2, part = tid & 3;
      const int bb = r0 / Lpix;           // 16-row tile never straddles b
      const int l0 = r0 - bb * Lpix;
      float4 o4;
      o4.x = tS[(part * 4 + 0) * 66 + c2];
      o4.y = tS[(part * 4 + 1) * 66 + c2];
      o4.z = tS[(part * 4 + 2) * 66 + c2];
      o4.w = tS[(part * 4 + 3) * 66 + c2];
      *(float4*)(oflt + (size_t)bb * strideB + (size_t)(col0 + c2) * Lpix +
                 l0 + part * 4) = o4;
    }
  }
}

// ======== chunked selective scan: 1 LANE-PAIR = 1 channel, 8 states/thread ======
// dts via register shfl (R12). S states stored bf16 (R13).
constexpr int SC_LC = 14;

__global__ __launch_bounds__(256) void k_scan1(
    const float* __restrict__ dtl, const __bf16* __restrict__ xi,
    const float* __restrict__ bc, const float* __restrict__ Wdt,
    const float* __restrict__ bdt, const float* __restrict__ A_log,
    float* __restrict__ DT, __bf16* __restrict__ S, int Lseq, int NC)
{
  __shared__ float Bs[SC_LC * 16];
  __shared__ float dtlS[SC_LC * 12];
  __shared__ float wdtS[12 * 128];
  const int t = threadIdx.x;
  const int el = t >> 1, half = t & 1, n0h = half * 8;
  const int e0 = blockIdx.y * 128;
  const int e = e0 + el;
  const int c = blockIdx.x % NC;
  const int b = blockIdx.x / NC;
  const int rowbase = b * Lseq + c * SC_LC;

  if (t < SC_LC * 16)
    Bs[t] = bc[(size_t)(rowbase + (t >> 4)) * 32 + (t & 15)];
  if (t < SC_LC * 12)
    dtlS[t] = dtl[(size_t)(rowbase + t / 12) * 12 + t % 12];
  for (int idx = t; idx < 12 * 128; idx += 256) {
    const int r = idx >> 7, ee = idx & 127;
    wdtS[idx] = Wdt[(size_t)(e0 + ee) * 12 + r];
  }
  const float bdte = bdt[e];

  float An2[8];
  {
    const float4* a4 = (const float4*)(A_log + e * 16 + n0h);
    float4 t0 = a4[0], t1 = a4[1];
    float tmp[8] = {t0.x, t0.y, t0.z, t0.w, t1.x, t1.y, t1.z, t1.w};
#pragma unroll
    for (int n = 0; n < 8; ++n) An2[n] = -__expf(tmp[n]) * 1.44269504f;
  }
  __syncthreads();

  float dto[7];
  float dtp = 0.f;
#pragma unroll
  for (int j = 0; j < 7; ++j) {
    const int l = half * 7 + j;
    float a = bdte;
#pragma unroll
    for (int r = 0; r < 12; ++r) a += dtlS[l * 12 + r] * wdtS[r * 128 + el];
    dto[j] = softplusf(a);
    dtp += dto[j];
  }
  const float dtsum = dtp + __shfl_xor(dtp, 1);
  float dts_r[SC_LC];
#pragma unroll
  for (int j = 0; j < 7; ++j) {
    const float oth = __shfl_xor(dto[j], 1);
    dts_r[j]     = half ? oth : dto[j];
    dts_r[7 + j] = half ? dto[j] : oth;
  }

  float xall[SC_LC];
#pragma unroll
  for (int l = 0; l < SC_LC; ++l)
    xall[l] = (float)xi[(size_t)(rowbase + l) * 384 + e];

  float h[8];
#pragma unroll
  for (int n = 0; n < 8; ++n) h[n] = 0.f;
#pragma unroll
  for (int l = 0; l < SC_LC; ++l) {
    const float dtv = dts_r[l];
    const float u = dtv * xall[l];
    const float* Brow = &Bs[l * 16 + n0h];
#pragma unroll
    for (int n = 0; n < 8; ++n) {
      const float a = __builtin_amdgcn_exp2f(dtv * An2[n]);
      h[n] = a * h[n] + u * Brow[n];
    }
  }
  const size_t o = ((size_t)(b * NC + c) * 384 + e) * 16 + n0h;
  bf16x8 hv;
#pragma unroll
  for (int n = 0; n < 8; ++n) hv[n] = (__bf16)h[n];
  *(bf16x8*)(S + o) = hv;
  if (half == 0) DT[(size_t)(b * NC + c) * 384 + e] = dtsum;
}

// carry: prefix-fold chunk (dtsum,S bf16) -> H0 in-place over S; fp32 registers,
// single rounding per stored prefix. Depth-8 batches, software double-buffer.
__global__ __launch_bounds__(256) void k_carry(
    const float* __restrict__ DT, __bf16* __restrict__ SH,
    const float* __restrict__ A_log, int NC)
{
  const int tid = blockIdx.x * 256 + threadIdx.x;   // 12288
  const int b = tid / 6144, r = tid % 6144;         // r = e*16 + n
  const float An2 = -__expf(A_log[r]) * 1.44269504f;
  const size_t o = (size_t)b * NC * 6144 + r;
  const size_t od = (size_t)b * NC * 384 + (r >> 4);

  float sA[8], dA[8], sB[8], dB[8];
  auto LOAD = [&](float (&sv)[8], float (&dv)[8], int c0) {
#pragma unroll
    for (int k = 0; k < 8; ++k) {
      sv[k] = (float)SH[o + (size_t)(c0 + k) * 6144];
      dv[k] = DT[od + (size_t)(c0 + k) * 384];
    }
  };
  float h = 0.f;
  auto COMP = [&](const float (&sv)[8], const float (&dv)[8], int c0) {
    float a[8];
#pragma unroll
    for (int k = 0; k < 8; ++k) a[k] = __builtin_amdgcn_exp2f(An2 * dv[k]);
#pragma unroll
    for (int k = 0; k < 8; ++k) {
      SH[o + (size_t)(c0 + k) * 6144] = (__bf16)h;
      h = a[k] * h + sv[k];
    }
  };

  LOAD(sA, dA, 0);
  for (int c0 = 0; c0 < NC; c0 += 16) {   // NC % 8 == 0 (224, 56)
    if (c0 + 8 < NC) LOAD(sB, dB, c0 + 8);
    COMP(sA, dA, c0);
    if (c0 + 8 < NC) {
      if (c0 + 16 < NC) LOAD(sA, dA, c0 + 16);
      COMP(sB, dB, c0 + 8);
    }
  }
}

// scan2: init from H0 (bf16), recompute chunk, gate with z (bf16), emit y
__global__ __launch_bounds__(256) void k_scan2(
    const float* __restrict__ dtl, const __bf16* __restrict__ xi,
    const float* __restrict__ bc, const __bf16* __restrict__ zB,
    const float* __restrict__ Wdt, const float* __restrict__ bdt,
    const float* __restrict__ A_log, const float* __restrict__ Dskip,
    const __bf16* __restrict__ H0, __bf16* __restrict__ y, int Lseq, int NC)
{
  __shared__ float BCs[SC_LC * 32];
  __shared__ float dtlS[SC_LC * 12];
  __shared__ float wdtS[12 * 128];
  const int t = threadIdx.x;
  const int el = t >> 1, half = t & 1, n0h = half * 8;
  const int e0 = blockIdx.y * 128;
  const int e = e0 + el;
  const int c = blockIdx.x % NC;
  const int b = blockIdx.x / NC;
  const int rowbase = b * Lseq + c * SC_LC;

  for (int idx = t; idx < SC_LC * 32; idx += 256)
    BCs[idx] = bc[(size_t)rowbase * 32 + idx];
  if (t < SC_LC * 12)
    dtlS[t] = dtl[(size_t)(rowbase + t / 12) * 12 + t % 12];
  for (int idx = t; idx < 12 * 128; idx += 256) {
    const int r = idx >> 7, ee = idx & 127;
    wdtS[idx] = Wdt[(size_t)(e0 + ee) * 12 + r];
  }
  const float bdte = bdt[e];

  float An2[8];
  {
    const float4* a4 = (const float4*)(A_log + e * 16 + n0h);
    float4 t0 = a4[0], t1 = a4[1];
    float tmp[8] = {t0.x, t0.y, t0.z, t0.w, t1.x, t1.y, t1.z, t1.w};
#pragma unroll
    for (int n = 0; n < 8; ++n) An2[n] = -__expf(tmp[n]) * 1.44269504f;
  }
  float h[8];
  {
    const size_t o = ((size_t)(b * NC + c) * 384 + e) * 16 + n0h;
    const bf16x8 h8 = *(const bf16x8*)(H0 + o);
#pragma unroll
    for (int n = 0; n < 8; ++n) h[n] = (float)h8[n];
  }
  __syncthreads();

  float dto[7];
#pragma unroll
  for (int j = 0; j < 7; ++j) {
    const int l = half * 7 + j;
    float a = bdte;
#pragma unroll
    for (int r = 0; r < 12; ++r) a += dtlS[l * 12 + r] * wdtS[r * 128 + el];
    dto[j] = softplusf(a);
  }
  float dts_r[SC_LC];
#pragma unroll
  for (int j = 0; j < 7; ++j) {
    const float oth = __shfl_xor(dto[j], 1);
    dts_r[j]     = half ? oth : dto[j];
    dts_r[7 + j] = half ? dto[j] : oth;
  }
  const float Dse = Dskip[e];

  float xall[SC_LC], zall[SC_LC];
#pragma unroll
  for (int l = 0; l < SC_LC; ++l) {
    const size_t r = (size_t)(rowbase + l);
    xall[l] = (float)xi[r * 384 + e];
    zall[l] = (float)zB[r * 384 + e];
  }

#pragma unroll
  for (int l = 0; l < SC_LC; ++l) {
    const float dtv = dts_r[l];
    const float xiv = xall[l];
    const float u = dtv * xiv;
    const float* Brow = &BCs[l * 32 + n0h];
    const float* Crow = &BCs[l * 32 + 16 + n0h];
    float yv = 0.f;
#pragma unroll
    for (int n = 0; n < 8; ++n) {
      const float a = __builtin_amdgcn_exp2f(dtv * An2[n]);
      h[n] = a * h[n] + u * Brow[n];
      yv += h[n] * Crow[n];
    }
    const float yt = yv + __shfl_xor(yv, 1);
    if (half == 0)
      y[(size_t)(rowbase + l) * 384 + e] = (__bf16)((yt + Dse * xiv) * siluf(zall[l]));
  }
}

extern "C" void kernel_launch(void* const* d_in, const int* in_sizes, int n_in,
                              void* d_out, int out_size, void* d_ws, size_t ws_size,
                              hipStream_t stream)
{
  const float* x    = (const float*)d_in[0];
  const float* pw   = (const float*)d_in[1];
  const float* pb   = (const float*)d_in[2];
  const float* bng  = (const float*)d_in[3];
  const float* bnb  = (const float*)d_in[4];
  const float* bnm  = (const float*)d_in[5];
  const float* bnv  = (const float*)d_in[6];
  const float* lng  = (const float*)d_in[7];
  const float* lnb  = (const float*)d_in[8];
  const float* Win  = (const float*)d_in[9];
  const float* b_in = (const float*)d_in[10];
  const float* cw   = (const float*)d_in[11];
  const float* cb   = (const float*)d_in[12];
  const float* Wx   = (const float*)d_in[13];
  const float* Wdt  = (const float*)d_in[14];
  const float* bdt  = (const float*)d_in[15];
  const float* Alog = (const float*)d_in[16];
  const float* Dsk  = (const float*)d_in[17];
  const float* Wout = (const float*)d_in[18];
  const float* bout = (const float*)d_in[19];

  float* wsf = (float*)d_ws;
  float* v    = wsf;                     // 1204224
  float* xz   = v + 1204224;             // 4816896 (x-half only; z -> zB bf16)
  float* dtlb = xz + 4816896;            // 75264
  float* bcb  = dtlb + 75264;            // 200704
  float* Sb   = bcb + 200704;            // S now bf16: uses half the slot
  float* Pb   = Sb + 2752512;            // DT: 172032 fp32; zB in tail
  __bf16* xiB = (__bf16*)(Pb + 2752512); // 2408448 bf16
  __bf16* yB  = (__bf16*)(Pb + 2752512 + 1204224);   // 2408448 bf16
  __bf16* Wb  = (__bf16*)(Pb + 2752512 + 2408448);   // 714240 bf16
  __bf16* Sh  = (__bf16*)Sb;                          // bf16 chunk states
  __bf16* zB  = (__bf16*)(Pb + 524288);               // 2408448 bf16 in Pb tail

  float* out0 = (float*)d_out;
  float* out1 = out0 + 301056;

  k_proj_wcvt<<<992, 256, 0, stream>>>(x, pw, pb, bng, bnb, bnm, bnv, v,
                                       Win, Wout, Wx, Wb);

  for (int i = 0; i < 3; ++i) {
    const int big = (i < 2) ? 1 : 0;
    const int Lseq = big ? 3136 : 784;
    const int M = 2 * Lseq;
    const int NC = Lseq / SC_LC;     // 224 big, 56 small
    const int MB = (M + 63) / 64;    // 98 big, 25 small
    const int MB16 = M / 16;         // 392 big, 98 small
    const float* lng_i = lng + i * 192;
    const float* lnb_i = lnb + i * 192;
    const float* bin_i = b_in + i * 768;
    const float* cw_i  = cw + i * 384 * 4;
    const float* cb_i  = cb + i * 384;
    const float* Wdt_i = Wdt + i * 384 * 12;
    const float* bdt_i = bdt + i * 384;
    const float* Al_i  = Alog + i * 384 * 16;
    const float* Ds_i  = Dsk + i * 384;
    const float* bo_i  = bout + i * 192;
    const __bf16* Winb_i  = Wb + i * 147456;
    const __bf16* Woutb_i = Wb + 442368 + i * 73728;
    const __bf16* Wxb_i   = Wb + 663552 + i * 16896;

    // xz = LN(src) @ Win^T + b_in  (streaming-W; x->xz fp32, z->zB bf16)
    if (big)
      k_gemm_xz<2><<<dim3(MB, 6), 256, 0, stream>>>(
          v, Winb_i, bin_i, xz, zB, M, lng_i, lnb_i);
    else
      k_gemm_xz<3><<<dim3(MB, 6), 256, 0, stream>>>(
          v, Winb_i, bin_i, xz, zB, M, lng_i, lnb_i);
    // depthwise conv + silu -> xiB bf16
    k_conv<<<(M * 384 / 8 + 255) / 256, 256, 0, stream>>>(
        xz, xiB, cw_i, cb_i, Lseq, M * 384 / 8);
    // proj (44 cols): writes dtl (M x 12) + bc (M x 32); 16-row streaming blocks
    k_gemm_s<EPI_G2><<<dim3(MB16, 1), 256, 0, stream>>>(
        xiB, Wxb_i, nullptr, nullptr, M, 384, 44, dtlb, bcb, nullptr);
    k_scan1<<<dim3(2 * NC, 3), 256, 0, stream>>>(
        dtlb, xiB, bcb, Wdt_i, bdt_i, Al_i, Pb, Sh, Lseq, NC);
    k_carry<<<48, 256, 0, stream>>>(Pb, Sh, Al_i, NC);
    k_scan2<<<dim3(2 * NC, 3), 256, 0, stream>>>(
        dtlb, xiB, bcb, zB, Wdt_i, bdt_i, Al_i, Ds_i, Sh, yB, Lseq, NC);
    if (i == 0)
      k_gemm_s<EPI_RES><<<dim3(MB16, 3), 256, 0, stream>>>(
          yB, Woutb_i, bo_i, v, M, 384, 192, nullptr, nullptr, nullptr);
    else if (i == 1)
      k_gemm_s<EPI_RES_SKIP><<<dim3(MB16, 3), 256, 0, stream>>>(
          yB, Woutb_i, bo_i, v, M, 384, 192, nullptr, nullptr, out1);
    else
      k_gemm_s<EPI_OUT2><<<dim3(MB16, 3), 256, 0, stream>>>(
          yB, Woutb_i, bo_i, v, M, 384, 192, nullptr, nullptr, out0);
  }
}

// Round 14
// 327.020 us; speedup vs baseline: 1.0541x; 1.0541x over previous
//
#include <hip/hip_runtime.h>

typedef __attribute__((ext_vector_type(8))) __bf16 bf16x8;
typedef __attribute__((ext_vector_type(4))) __bf16 bf16x4;
typedef __attribute__((ext_vector_type(4))) float f32x4;

#define DEV static __device__ __forceinline__

DEV float fast_rcp(float x) { return __builtin_amdgcn_rcpf(x); }
DEV float sigm(float x) { return fast_rcp(1.f + __expf(-x)); }
DEV float siluf(float x) { return x * sigm(x); }
DEV float softplusf(float x) { return x > 20.f ? x : __logf(1.f + __expf(x)); }

// R3: no in-kernel grid sync. R5/R9/R11: fusion must DELETE work, not move it
// into a latency-bound consumer. R6/R7: stream W from L2. R8: pair-split scan.
// R10: coalesce transposed stores via LDS. R12: dts via register shfl-exchange.
// R13 (reverted): bf16 demotion of S/z regressed +17us -- latency-bound, not
// traffic-bound; 2B scalar access patterns cost more than the bytes saved.

// ---------------- proj (96->192) MFMA GEMM + BN  ||  weight fp32->bf16 convert ----
__global__ __launch_bounds__(256) void k_proj_wcvt(
    const float* __restrict__ x, const float* __restrict__ pw,
    const float* __restrict__ pb, const float* __restrict__ bng,
    const float* __restrict__ bnb, const float* __restrict__ bnm,
    const float* __restrict__ bnv, float* __restrict__ v,
    const float* __restrict__ Win, const float* __restrict__ Wout,
    const float* __restrict__ Wx, __bf16* __restrict__ Wb)
{
  constexpr int SAP = 104;
  __shared__ __bf16 As[64 * SAP];
  __shared__ __bf16 Ws[64 * SAP];
  const int tid = threadIdx.x;
  const int bid = blockIdx.x;

  if (bid >= 294) {            // ---- wcvt part, float4-vectorized ----
    const int idx = ((bid - 294) * 256 + tid) * 4;   // segments all %4==0
    if (idx < 714240) {
      const float* src;
      if (idx < 442368) src = Win + idx;
      else if (idx < 663552) src = Wout + (idx - 442368);
      else src = Wx + (idx - 663552);
      const float4 tv = *(const float4*)src;
      bf16x4 o;
      o[0] = (__bf16)tv.x; o[1] = (__bf16)tv.y;
      o[2] = (__bf16)tv.z; o[3] = (__bf16)tv.w;
      *(bf16x4*)(Wb + idx) = o;
    }
    return;
  }

  const int r0 = (bid % 98) * 64;
  const int col0 = (bid / 98) * 64;
  const int b = r0 / 3136, l0 = r0 % 3136;
  const int lane = tid & 63, wv = tid >> 6;
  const int rh = wv >> 1, ch = wv & 1;
  const int lm = lane & 15, quad = lane >> 4;

#pragma unroll
  for (int it = 0; it < 6; ++it) {
    const int idx = tid + it * 256;
    const int c = idx >> 4, l4 = idx & 15;
    const float4 t = *(const float4*)(x + ((size_t)(b * 96 + c)) * 3136 + l0 + l4 * 4);
    As[(l4 * 4 + 0) * SAP + c] = (__bf16)t.x;
    As[(l4 * 4 + 1) * SAP + c] = (__bf16)t.y;
    As[(l4 * 4 + 2) * SAP + c] = (__bf16)t.z;
    As[(l4 * 4 + 3) * SAP + c] = (__bf16)t.w;
  }
#pragma unroll
  for (int it = 0; it < 6; ++it) {
    const int idx = tid + it * 256;
    const int wr = idx / 24, kc = (idx % 24) * 4;
    const float4 t = *(const float4*)(pw + (size_t)(col0 + wr) * 96 + kc);
    bf16x4 o;
    o[0] = (__bf16)t.x; o[1] = (__bf16)t.y; o[2] = (__bf16)t.z; o[3] = (__bf16)t.w;
    *(bf16x4*)(&Ws[wr * SAP + kc]) = o;
  }
  __syncthreads();

  f32x4 acc[2][2] = {};
#pragma unroll
  for (int ks = 0; ks < 3; ++ks) {
    const int kb = ks * 32 + quad * 8;
    bf16x8 a0 = *(const bf16x8*)(&As[(rh * 32 + lm) * SAP + kb]);
    bf16x8 a1 = *(const bf16x8*)(&As[(rh * 32 + 16 + lm) * SAP + kb]);
    bf16x8 b0 = *(const bf16x8*)(&Ws[(ch * 32 + lm) * SAP + kb]);
    bf16x8 b1 = *(const bf16x8*)(&Ws[(ch * 32 + 16 + lm) * SAP + kb]);
    acc[0][0] = __builtin_amdgcn_mfma_f32_16x16x32_bf16(a0, b0, acc[0][0], 0, 0, 0);
    acc[0][1] = __builtin_amdgcn_mfma_f32_16x16x32_bf16(a0, b1, acc[0][1], 0, 0, 0);
    acc[1][0] = __builtin_amdgcn_mfma_f32_16x16x32_bf16(a1, b0, acc[1][0], 0, 0, 0);
    acc[1][1] = __builtin_amdgcn_mfma_f32_16x16x32_bf16(a1, b1, acc[1][1], 0, 0, 0);
  }

#pragma unroll
  for (int ti = 0; ti < 2; ++ti)
#pragma unroll
    for (int tj = 0; tj < 2; ++tj) {
      const int gcol = col0 + ch * 32 + tj * 16 + lm;
      const float s = rsqrtf(bnv[gcol] + 1e-5f) * bng[gcol];
      const float sh = (pb[gcol] - bnm[gcol]) * s + bnb[gcol];
#pragma unroll
      for (int j = 0; j < 4; ++j) {
        const int grow = r0 + rh * 32 + ti * 16 + quad * 4 + j;
        v[(size_t)grow * 192 + gcol] = acc[ti][tj][j] * s + sh;
      }
    }
}

// ---------------- depthwise causal conv K=4 + silu, 8 outputs/thread -> xiB bf16 ----
__global__ __launch_bounds__(256) void k_conv(
    const float* __restrict__ xz, __bf16* __restrict__ xiB,
    const float* __restrict__ cw, const float* __restrict__ cb,
    int Lseq, int nthreads)
{
  const int idx = blockIdx.x * 256 + threadIdx.x;
  if (idx >= nthreads) return;
  const int e = idx % 384;
  const int seg = idx / 384;
  const int nseg = Lseq / 8;
  const int b = seg / nseg;
  const int l0 = (seg % nseg) * 8;
  const float4 w4 = *(const float4*)(cw + e * 4);
  const float bv = cb[e];
  float xv[11];
#pragma unroll
  for (int k = 0; k < 11; ++k) {
    const int l = l0 - 3 + k;
    xv[k] = (l >= 0) ? xz[(size_t)(b * Lseq + l) * 768 + e] : 0.f;
  }
#pragma unroll
  for (int j = 0; j < 8; ++j) {
    const float a = bv + xv[j] * w4.x + xv[j + 1] * w4.y + xv[j + 2] * w4.z + xv[j + 3] * w4.w;
    xiB[(size_t)(b * Lseq + l0 + j) * 384 + e] = (__bf16)siluf(a);
  }
}

// ---------------- xz GEMM (K=192, N=768): LN(A) @ Win^T + b, streaming W ---------
template <int AMODE>
__global__ __launch_bounds__(256, 4) void k_gemm_xz(
    const float* __restrict__ A, const __bf16* __restrict__ W,
    const float* __restrict__ bias, float* __restrict__ O,
    int M, const float* __restrict__ lng, const float* __restrict__ lnb)
{
  constexpr int SA = 200;
  __shared__ __bf16 As[64 * SA];
  __shared__ float lnS[384];
  const int tid = threadIdx.x;
  const int r0 = blockIdx.x * 64;
  const int col0 = blockIdx.y * 128;
  const int lane = tid & 63, wv = tid >> 6;
  const int rh = wv & 1, ch = wv >> 1;
  const int lm = lane & 15, quad = lane >> 4;

  if (tid < 192) { lnS[tid] = lng[tid]; lnS[192 + tid] = lnb[tid]; }
  __syncthreads();

  // ---- stage A: 4 lanes per row, LN fused, bf16 out ----
  {
    const int row = tid >> 2, part = tid & 3;
    const int gr = min(r0 + row, M - 1);
    const int cbase = part * 48;
    float4 tv[12];
    if constexpr (AMODE == 2) {
#pragma unroll
      for (int j = 0; j < 12; ++j)
        tv[j] = *(const float4*)(A + (size_t)gr * 192 + cbase + j * 4);
    } else {  // maxpool2 of v (B,3136,192); gr is pooled pixel index
      const int bb = gr / 784, l2 = gr % 784;
      const int h2 = l2 / 28, w2 = l2 % 28;
      const float* p0 = A + (size_t)(bb * 3136 + h2 * 112 + w2 * 2) * 192;
#pragma unroll
      for (int j = 0; j < 12; ++j) {
        const int cc = cbase + j * 4;
        const float4 a0 = *(const float4*)(p0 + cc);
        const float4 a1 = *(const float4*)(p0 + 192 + cc);
        const float4 a2 = *(const float4*)(p0 + 56 * 192 + cc);
        const float4 a3 = *(const float4*)(p0 + 57 * 192 + cc);
        tv[j].x = fmaxf(fmaxf(a0.x, a1.x), fmaxf(a2.x, a3.x));
        tv[j].y = fmaxf(fmaxf(a0.y, a1.y), fmaxf(a2.y, a3.y));
        tv[j].z = fmaxf(fmaxf(a0.z, a1.z), fmaxf(a2.z, a3.z));
        tv[j].w = fmaxf(fmaxf(a0.w, a1.w), fmaxf(a2.w, a3.w));
      }
    }
    float s = 0.f, sq = 0.f;
#pragma unroll
    for (int j = 0; j < 12; ++j) {
      s += tv[j].x + tv[j].y + tv[j].z + tv[j].w;
      sq += tv[j].x * tv[j].x + tv[j].y * tv[j].y + tv[j].z * tv[j].z + tv[j].w * tv[j].w;
    }
    s += __shfl_xor(s, 1); s += __shfl_xor(s, 2);
    sq += __shfl_xor(sq, 1); sq += __shfl_xor(sq, 2);
    const float mean = s * (1.f / 192.f);
    const float rstd = rsqrtf(sq * (1.f / 192.f) - mean * mean + 1e-5f);
#pragma unroll
    for (int j = 0; j < 12; ++j) {
      const int c = cbase + j * 4;
      bf16x4 o;
      o[0] = (__bf16)((tv[j].x - mean) * rstd * lnS[c + 0] + lnS[192 + c + 0]);
      o[1] = (__bf16)((tv[j].y - mean) * rstd * lnS[c + 1] + lnS[192 + c + 1]);
      o[2] = (__bf16)((tv[j].z - mean) * rstd * lnS[c + 2] + lnS[192 + c + 2]);
      o[3] = (__bf16)((tv[j].w - mean) * rstd * lnS[c + 3] + lnS[192 + c + 3]);
      *(bf16x4*)(&As[row * SA + c]) = o;
    }
  }
  __syncthreads();

  // ---- MFMA, B streamed from global ----
  f32x4 acc[2][4] = {};
#pragma unroll
  for (int ks = 0; ks < 6; ++ks) {
    const int kb = ks * 32 + quad * 8;
    bf16x8 a0 = *(const bf16x8*)(&As[(rh * 32 + lm) * SA + kb]);
    bf16x8 a1 = *(const bf16x8*)(&As[(rh * 32 + 16 + lm) * SA + kb]);
#pragma unroll
    for (int tj = 0; tj < 4; ++tj) {
      const int gw = col0 + ch * 64 + tj * 16 + lm;
      bf16x8 bfr = *(const bf16x8*)(W + (size_t)gw * 192 + kb);
      acc[0][tj] = __builtin_amdgcn_mfma_f32_16x16x32_bf16(a0, bfr, acc[0][tj], 0, 0, 0);
      acc[1][tj] = __builtin_amdgcn_mfma_f32_16x16x32_bf16(a1, bfr, acc[1][tj], 0, 0, 0);
    }
  }

  // ---- epilogue: write xz ----
#pragma unroll
  for (int ti = 0; ti < 2; ++ti)
#pragma unroll
    for (int tj = 0; tj < 4; ++tj) {
      const int gcol = col0 + ch * 64 + tj * 16 + lm;
      const float bv = bias[gcol];
#pragma unroll
      for (int j = 0; j < 4; ++j) {
        const int rowt = rh * 32 + ti * 16 + quad * 4 + j;
        const int grow = r0 + rowt;
        if (grow < M) O[(size_t)grow * 768 + gcol] = acc[ti][tj][j] + bv;
      }
    }
}

// ------- streaming-W small-N GEMM, 16-row x 64-col blocks, A-only LDS ----------
// Transposed outputs (RES_SKIP/OUT2) via LDS tile + float4-contiguous stores.
constexpr int EPI_G2 = 1, EPI_RES = 2, EPI_RES_SKIP = 3, EPI_OUT2 = 4;

template <int EPI>
__global__ __launch_bounds__(256) void k_gemm_s(
    const __bf16* __restrict__ Ab, const __bf16* __restrict__ W,
    const float* __restrict__ bias, float* __restrict__ O,
    int M, int K, int Nvalid,
    float* __restrict__ dtlbuf, float* __restrict__ bcbuf,
    float* __restrict__ oflt)
{
  constexpr int SA = 200;
  __shared__ __align__(16) char smem[16 * SA * 2];   // As (6400B) / tS (4224B)
  __bf16* As = (__bf16*)smem;
  __shared__ float dtlS[(EPI == EPI_G2) ? 16 * 12 : 1];
  const int tid = threadIdx.x;
  const int r0 = blockIdx.x * 16;
  const int col0 = blockIdx.y * 64;
  const int lane = tid & 63, wv = tid >> 6;
  const int ch = wv;
  const int lm = lane & 15, quad = lane >> 4;

  f32x4 acc = {};
  const int nkp = K / 192;
  for (int kp = 0; kp < nkp; ++kp) {
    if (kp) __syncthreads();
    {
      const int idx = tid;                 // 0..255
      const int row = idx / 24, kc = (idx % 24) * 8;
      const int gr = min(r0 + row, M - 1);
      if (row < 16)
        *(bf16x8*)(&As[row * SA + kc]) =
            *(const bf16x8*)(Ab + (size_t)gr * K + kp * 192 + kc);
      const int idx2 = tid + 256;
      if (idx2 < 384) {
        const int row2 = idx2 / 24, kc2 = (idx2 % 24) * 8;
        const int gr2 = min(r0 + row2, M - 1);
        *(bf16x8*)(&As[row2 * SA + kc2]) =
            *(const bf16x8*)(Ab + (size_t)gr2 * K + kp * 192 + kc2);
      }
    }
    __syncthreads();
#pragma unroll
    for (int ks = 0; ks < 6; ++ks) {
      const int kb = ks * 32 + quad * 8;
      bf16x8 a0 = *(const bf16x8*)(&As[lm * SA + kb]);
      const int gw = min(col0 + ch * 16 + lm, Nvalid - 1);  // clamp: cols >= Nvalid discarded
      bf16x8 bfr = *(const bf16x8*)(W + (size_t)gw * K + kp * 192 + kb);
      acc = __builtin_amdgcn_mfma_f32_16x16x32_bf16(a0, bfr, acc, 0, 0, 0);
    }
  }

  // ---- epilogue ----
  const int colt = ch * 16 + lm;
  if constexpr (EPI == EPI_G2) {
#pragma unroll
    for (int j = 0; j < 4; ++j) {
      const int rowt = quad * 4 + j;
      const int grow = r0 + rowt;
      const float val = acc[j];
      if (colt < 12) dtlS[rowt * 12 + colt] = val;
      else if (colt < 44 && grow < M)
        bcbuf[(size_t)grow * 32 + (colt - 12)] = val;
    }
    __syncthreads();
    if (tid < 192) {
      const int grow = r0 + tid / 12;
      if (grow < M) dtlbuf[(size_t)grow * 12 + tid % 12] = dtlS[tid];
    }
  } else {
    const int gcol = col0 + colt;
    const float bv = bias[gcol];
    float nv4[4];
#pragma unroll
    for (int j = 0; j < 4; ++j) {
      const int rowt = quad * 4 + j;
      const int grow = r0 + rowt;      // grid = M/16 exactly -> always < M
      const float val = acc[j] + bv;
      if constexpr (EPI == EPI_RES) {
        O[(size_t)grow * 192 + gcol] += val;
      } else if constexpr (EPI == EPI_RES_SKIP) {
        const float nvv = O[(size_t)grow * 192 + gcol] + val;
        O[(size_t)grow * 192 + gcol] = nvv;
        nv4[j] = nvv;
      } else {  // EPI_OUT2
        nv4[j] = val;
      }
    }
    if constexpr (EPI == EPI_RES_SKIP || EPI == EPI_OUT2) {
      float* tS = (float*)smem;           // [16][66] fp32 overlaying As
      __syncthreads();                    // all As reads done
#pragma unroll
      for (int j = 0; j < 4; ++j)
        tS[(quad * 4 + j) * 66 + colt] = nv4[j];
      __syncthreads();
      // coalesced transposed store: thread -> (gcol2 = tid>>2, 4 rows)
      constexpr int Lpix = (EPI == EPI_RES_SKIP) ? 3136 : 784;
      constexpr int strideB = (EPI == EPI_RES_SKIP) ? 602112 : 150528;
      const int c2 = tid >> 2, part = tid & 3;
      const int bb = r0 / Lpix;           // 16-row tile never straddles b
      const int l0 = r0 - bb * Lpix;
      float4 o4;
      o4.x = tS[(part * 4 + 0) * 66 + c2];
      o4.y = tS[(part * 4 + 1) * 66 + c2];
      o4.z = tS[(part * 4 + 2) * 66 + c2];
      o4.w = tS[(part * 4 + 3) * 66 + c2];
      *(float4*)(oflt + (size_t)bb * strideB + (size_t)(col0 + c2) * Lpix +
                 l0 + part * 4) = o4;
    }
  }
}

// ======== chunked selective scan: 1 LANE-PAIR = 1 channel, 8 states/thread ======
// dt-projection split across the pair (7 rows each); the partner's 7 dts come
// via register __shfl_xor(.,1) (R12: no dts LDS array, no extra sync).
constexpr int SC_LC = 14;

__global__ __launch_bounds__(256) void k_scan1(
    const float* __restrict__ dtl, const __bf16* __restrict__ xi,
    const float* __restrict__ bc, const float* __restrict__ Wdt,
    const float* __restrict__ bdt, const float* __restrict__ A_log,
    float* __restrict__ DT, float* __restrict__ S, int Lseq, int NC)
{
  __shared__ float Bs[SC_LC * 16];
  __shared__ float dtlS[SC_LC * 12];
  __shared__ float wdtS[12 * 128];
  const int t = threadIdx.x;
  const int el = t >> 1, half = t & 1, n0h = half * 8;
  const int e0 = blockIdx.y * 128;
  const int e = e0 + el;
  const int c = blockIdx.x % NC;
  const int b = blockIdx.x / NC;
  const int rowbase = b * Lseq + c * SC_LC;

  if (t < SC_LC * 16)
    Bs[t] = bc[(size_t)(rowbase + (t >> 4)) * 32 + (t & 15)];
  if (t < SC_LC * 12)
    dtlS[t] = dtl[(size_t)(rowbase + t / 12) * 12 + t % 12];
  for (int idx = t; idx < 12 * 128; idx += 256) {
    const int r = idx >> 7, ee = idx & 127;
    wdtS[idx] = Wdt[(size_t)(e0 + ee) * 12 + r];
  }
  const float bdte = bdt[e];

  float An2[8];
  {
    const float4* a4 = (const float4*)(A_log + e * 16 + n0h);
    float4 t0 = a4[0], t1 = a4[1];
    float tmp[8] = {t0.x, t0.y, t0.z, t0.w, t1.x, t1.y, t1.z, t1.w};
#pragma unroll
    for (int n = 0; n < 8; ++n) An2[n] = -__expf(tmp[n]) * 1.44269504f;
  }
  __syncthreads();

  // 7 own dts in regs; partner's 7 via shfl (compile-time indices only)
  float dto[7];
  float dtp = 0.f;
#pragma unroll
  for (int j = 0; j < 7; ++j) {
    const int l = half * 7 + j;
    float a = bdte;
#pragma unroll
    for (int r = 0; r < 12; ++r) a += dtlS[l * 12 + r] * wdtS[r * 128 + el];
    dto[j] = softplusf(a);
    dtp += dto[j];
  }
  const float dtsum = dtp + __shfl_xor(dtp, 1);
  float dts_r[SC_LC];
#pragma unroll
  for (int j = 0; j < 7; ++j) {
    const float oth = __shfl_xor(dto[j], 1);
    dts_r[j]     = half ? oth : dto[j];
    dts_r[7 + j] = half ? dto[j] : oth;
  }

  float xall[SC_LC];
#pragma unroll
  for (int l = 0; l < SC_LC; ++l)
    xall[l] = (float)xi[(size_t)(rowbase + l) * 384 + e];

  float h[8];
#pragma unroll
  for (int n = 0; n < 8; ++n) h[n] = 0.f;
#pragma unroll
  for (int l = 0; l < SC_LC; ++l) {
    const float dtv = dts_r[l];
    const float u = dtv * xall[l];
    const float* Brow = &Bs[l * 16 + n0h];
#pragma unroll
    for (int n = 0; n < 8; ++n) {
      const float a = __builtin_amdgcn_exp2f(dtv * An2[n]);
      h[n] = a * h[n] + u * Brow[n];
    }
  }
  const size_t o = ((size_t)(b * NC + c) * 384 + e) * 16 + n0h;
  *(float4*)(S + o)     = make_float4(h[0], h[1], h[2], h[3]);
  *(float4*)(S + o + 4) = make_float4(h[4], h[5], h[6], h[7]);
  if (half == 0) DT[(size_t)(b * NC + c) * 384 + e] = dtsum;
}

// carry: prefix-fold chunk (dtsum,S) -> H0 in-place over S; depth-8 batches,
// software double-buffer (192 waves total -> ILP is all it has).
__global__ __launch_bounds__(256) void k_carry(
    const float* __restrict__ DT, float* __restrict__ SH,
    const float* __restrict__ A_log, int NC)
{
  const int tid = blockIdx.x * 256 + threadIdx.x;   // 12288
  const int b = tid / 6144, r = tid % 6144;         // r = e*16 + n
  const float An2 = -__expf(A_log[r]) * 1.44269504f;
  const size_t o = (size_t)b * NC * 6144 + r;
  const size_t od = (size_t)b * NC * 384 + (r >> 4);

  float sA[8], dA[8], sB[8], dB[8];
  auto LOAD = [&](float (&sv)[8], float (&dv)[8], int c0) {
#pragma unroll
    for (int k = 0; k < 8; ++k) {
      sv[k] = SH[o + (size_t)(c0 + k) * 6144];
      dv[k] = DT[od + (size_t)(c0 + k) * 384];
    }
  };
  float h = 0.f;
  auto COMP = [&](const float (&sv)[8], const float (&dv)[8], int c0) {
    float a[8];
#pragma unroll
    for (int k = 0; k < 8; ++k) a[k] = __builtin_amdgcn_exp2f(An2 * dv[k]);
#pragma unroll
    for (int k = 0; k < 8; ++k) {
      SH[o + (size_t)(c0 + k) * 6144] = h;
      h = a[k] * h + sv[k];
    }
  };

  LOAD(sA, dA, 0);
  for (int c0 = 0; c0 < NC; c0 += 16) {   // NC % 8 == 0 (224, 56)
    if (c0 + 8 < NC) LOAD(sB, dB, c0 + 8);
    COMP(sA, dA, c0);
    if (c0 + 8 < NC) {
      if (c0 + 16 < NC) LOAD(sA, dA, c0 + 16);
      COMP(sB, dB, c0 + 8);
    }
  }
}

// scan2: init from H0, recompute chunk with pair-split states, emit gated y
__global__ __launch_bounds__(256) void k_scan2(
    const float* __restrict__ dtl, const __bf16* __restrict__ xi,
    const float* __restrict__ bc, const float* __restrict__ xz,
    const float* __restrict__ Wdt, const float* __restrict__ bdt,
    const float* __restrict__ A_log, const float* __restrict__ Dskip,
    const float* __restrict__ H0, __bf16* __restrict__ y, int Lseq, int NC)
{
  __shared__ float BCs[SC_LC * 32];
  __shared__ float dtlS[SC_LC * 12];
  __shared__ float wdtS[12 * 128];
  const int t = threadIdx.x;
  const int el = t >> 1, half = t & 1, n0h = half * 8;
  const int e0 = blockIdx.y * 128;
  const int e = e0 + el;
  const int c = blockIdx.x % NC;
  const int b = blockIdx.x / NC;
  const int rowbase = b * Lseq + c * SC_LC;

  for (int idx = t; idx < SC_LC * 32; idx += 256)
    BCs[idx] = bc[(size_t)rowbase * 32 + idx];
  if (t < SC_LC * 12)
    dtlS[t] = dtl[(size_t)(rowbase + t / 12) * 12 + t % 12];
  for (int idx = t; idx < 12 * 128; idx += 256) {
    const int r = idx >> 7, ee = idx & 127;
    wdtS[idx] = Wdt[(size_t)(e0 + ee) * 12 + r];
  }
  const float bdte = bdt[e];

  float An2[8];
  {
    const float4* a4 = (const float4*)(A_log + e * 16 + n0h);
    float4 t0 = a4[0], t1 = a4[1];
    float tmp[8] = {t0.x, t0.y, t0.z, t0.w, t1.x, t1.y, t1.z, t1.w};
#pragma unroll
    for (int n = 0; n < 8; ++n) An2[n] = -__expf(tmp[n]) * 1.44269504f;
  }
  float h[8];
  {
    const size_t o = ((size_t)(b * NC + c) * 384 + e) * 16 + n0h;
    const float4* h4 = (const float4*)(H0 + o);
    float4 t0 = h4[0], t1 = h4[1];
    h[0]=t0.x; h[1]=t0.y; h[2]=t0.z; h[3]=t0.w;
    h[4]=t1.x; h[5]=t1.y; h[6]=t1.z; h[7]=t1.w;
  }
  __syncthreads();

  float dto[7];
#pragma unroll
  for (int j = 0; j < 7; ++j) {
    const int l = half * 7 + j;
    float a = bdte;
#pragma unroll
    for (int r = 0; r < 12; ++r) a += dtlS[l * 12 + r] * wdtS[r * 128 + el];
    dto[j] = softplusf(a);
  }
  float dts_r[SC_LC];
#pragma unroll
  for (int j = 0; j < 7; ++j) {
    const float oth = __shfl_xor(dto[j], 1);
    dts_r[j]     = half ? oth : dto[j];
    dts_r[7 + j] = half ? dto[j] : oth;
  }
  const float Dse = Dskip[e];

  float xall[SC_LC], zall[SC_LC];
#pragma unroll
  for (int l = 0; l < SC_LC; ++l) {
    const size_t r = (size_t)(rowbase + l);
    xall[l] = (float)xi[r * 384 + e];
    zall[l] = xz[r * 768 + 384 + e];
  }

#pragma unroll
  for (int l = 0; l < SC_LC; ++l) {
    const float dtv = dts_r[l];
    const float xiv = xall[l];
    const float u = dtv * xiv;
    const float* Brow = &BCs[l * 32 + n0h];
    const float* Crow = &BCs[l * 32 + 16 + n0h];
    float yv = 0.f;
#pragma unroll
    for (int n = 0; n < 8; ++n) {
      const float a = __builtin_amdgcn_exp2f(dtv * An2[n]);
      h[n] = a * h[n] + u * Brow[n];
      yv += h[n] * Crow[n];
    }
    const float yt = yv + __shfl_xor(yv, 1);
    if (half == 0)
      y[(size_t)(rowbase + l) * 384 + e] = (__bf16)((yt + Dse * xiv) * siluf(zall[l]));
  }
}

extern "C" void kernel_launch(void* const* d_in, const int* in_sizes, int n_in,
                              void* d_out, int out_size, void* d_ws, size_t ws_size,
                              hipStream_t stream)
{
  const float* x    = (const float*)d_in[0];
  const float* pw   = (const float*)d_in[1];
  const float* pb   = (const float*)d_in[2];
  const float* bng  = (const float*)d_in[3];
  const float* bnb  = (const float*)d_in[4];
  const float* bnm  = (const float*)d_in[5];
  const float* bnv  = (const float*)d_in[6];
  const float* lng  = (const float*)d_in[7];
  const float* lnb  = (const float*)d_in[8];
  const float* Win  = (const float*)d_in[9];
  const float* b_in = (const float*)d_in[10];
  const float* cw   = (const float*)d_in[11];
  const float* cb   = (const float*)d_in[12];
  const float* Wx   = (const float*)d_in[13];
  const float* Wdt  = (const float*)d_in[14];
  const float* bdt  = (const float*)d_in[15];
  const float* Alog = (const float*)d_in[16];
  const float* Dsk  = (const float*)d_in[17];
  const float* Wout = (const float*)d_in[18];
  const float* bout = (const float*)d_in[19];

  float* wsf = (float*)d_ws;
  float* v    = wsf;                     // 1204224
  float* xz   = v + 1204224;             // 4816896
  float* dtlb = xz + 4816896;            // 75264
  float* bcb  = dtlb + 75264;            // 200704
  float* Sb   = bcb + 200704;            // 2752512 (NC up to 224)
  float* Pb   = Sb + 2752512;            // dtsum: 172032 used (slot kept)
  __bf16* xiB = (__bf16*)(Pb + 2752512); // 2408448 bf16
  __bf16* yB  = (__bf16*)(Pb + 2752512 + 1204224);   // 2408448 bf16
  __bf16* Wb  = (__bf16*)(Pb + 2752512 + 2408448);   // 714240 bf16

  float* out0 = (float*)d_out;
  float* out1 = out0 + 301056;

  k_proj_wcvt<<<992, 256, 0, stream>>>(x, pw, pb, bng, bnb, bnm, bnv, v,
                                       Win, Wout, Wx, Wb);

  for (int i = 0; i < 3; ++i) {
    const int big = (i < 2) ? 1 : 0;
    const int Lseq = big ? 3136 : 784;
    const int M = 2 * Lseq;
    const int NC = Lseq / SC_LC;     // 224 big, 56 small
    const int MB = (M + 63) / 64;    // 98 big, 25 small
    const int MB16 = M / 16;         // 392 big, 98 small
    const float* lng_i = lng + i * 192;
    const float* lnb_i = lnb + i * 192;
    const float* bin_i = b_in + i * 768;
    const float* cw_i  = cw + i * 384 * 4;
    const float* cb_i  = cb + i * 384;
    const float* Wdt_i = Wdt + i * 384 * 12;
    const float* bdt_i = bdt + i * 384;
    const float* Al_i  = Alog + i * 384 * 16;
    const float* Ds_i  = Dsk + i * 384;
    const float* bo_i  = bout + i * 192;
    const __bf16* Winb_i  = Wb + i * 147456;
    const __bf16* Woutb_i = Wb + 442368 + i * 73728;
    const __bf16* Wxb_i   = Wb + 663552 + i * 16896;

    // xz = LN(src) @ Win^T + b_in  (streaming-W, 4 blk/CU)
    if (big)
      k_gemm_xz<2><<<dim3(MB, 6), 256, 0, stream>>>(
          v, Winb_i, bin_i, xz, M, lng_i, lnb_i);
    else
      k_gemm_xz<3><<<dim3(MB, 6), 256, 0, stream>>>(
          v, Winb_i, bin_i, xz, M, lng_i, lnb_i);
    // depthwise conv + silu -> xiB bf16
    k_conv<<<(M * 384 / 8 + 255) / 256, 256, 0, stream>>>(
        xz, xiB, cw_i, cb_i, Lseq, M * 384 / 8);
    // proj (44 cols): writes dtl (M x 12) + bc (M x 32); 16-row streaming blocks
    k_gemm_s<EPI_G2><<<dim3(MB16, 1), 256, 0, stream>>>(
        xiB, Wxb_i, nullptr, nullptr, M, 384, 44, dtlb, bcb, nullptr);
    k_scan1<<<dim3(2 * NC, 3), 256, 0, stream>>>(
        dtlb, xiB, bcb, Wdt_i, bdt_i, Al_i, Pb, Sb, Lseq, NC);
    k_carry<<<48, 256, 0, stream>>>(Pb, Sb, Al_i, NC);
    k_scan2<<<dim3(2 * NC, 3), 256, 0, stream>>>(
        dtlb, xiB, bcb, xz, Wdt_i, bdt_i, Al_i, Ds_i, Sb, yB, Lseq, NC);
    if (i == 0)
      k_gemm_s<EPI_RES><<<dim3(MB16, 3), 256, 0, stream>>>(
          yB, Woutb_i, bo_i, v, M, 384, 192, nullptr, nullptr, nullptr);
    else if (i == 1)
      k_gemm_s<EPI_RES_SKIP><<<dim3(MB16, 3), 256, 0, stream>>>(
          yB, Woutb_i, bo_i, v, M, 384, 192, nullptr, nullptr, out1);
    else
      k_gemm_s<EPI_OUT2><<<dim3(MB16, 3), 256, 0, stream>>>(
          yB, Woutb_i, bo_i, v, M, 384, 192, nullptr, nullptr, out0);
  }
}

// Round 15
// 325.326 us; speedup vs baseline: 1.0596x; 1.0052x over previous
//
#include <hip/hip_runtime.h>

typedef __attribute__((ext_vector_type(8))) __bf16 bf16x8;
typedef __attribute__((ext_vector_type(4))) __bf16 bf16x4;
typedef __attribute__((ext_vector_type(4))) float f32x4;

#define DEV static __device__ __forceinline__

DEV float fast_rcp(float x) { return __builtin_amdgcn_rcpf(x); }
DEV float sigm(float x) { return fast_rcp(1.f + __expf(-x)); }
DEV float siluf(float x) { return x * sigm(x); }
DEV float softplusf(float x) { return x > 20.f ? x : __logf(1.f + __expf(x)); }

// Ledger: R3 no in-kernel grid sync (non-coherent per-XCD L2). R5/R9/R11:
// fusion must DELETE work, not move it into latency-bound consumers. R6/R7:
// stream W from L2 for small-N GEMMs. R8: pair-split scan (TLP). R10:
// LDS-coalesced transposed stores. R12: dts via register shfl. R13 (reverted):
// bf16 demotion of S/z -- latency-bound pipeline, partial-sector writes cost
// more than bytes saved. R15: Wdt pre-transposed -> coalesced scan staging.

// ---------------- proj (96->192) MFMA GEMM + BN  ||  weight fp32->bf16 convert ----
__global__ __launch_bounds__(256) void k_proj_wcvt(
    const float* __restrict__ x, const float* __restrict__ pw,
    const float* __restrict__ pb, const float* __restrict__ bng,
    const float* __restrict__ bnb, const float* __restrict__ bnm,
    const float* __restrict__ bnv, float* __restrict__ v,
    const float* __restrict__ Win, const float* __restrict__ Wout,
    const float* __restrict__ Wx, __bf16* __restrict__ Wb,
    const float* __restrict__ Wdt, float* __restrict__ WdtT)
{
  constexpr int SAP = 104;
  __shared__ __bf16 As[64 * SAP];
  __shared__ __bf16 Ws[64 * SAP];
  const int tid = threadIdx.x;
  const int bid = blockIdx.x;

  if (bid >= 992) {            // ---- Wdt transpose: (3,384,12) -> (3,12,384) ----
    const int o = (bid - 992) * 256 + tid;
    if (o < 13824) {
      const int i = o / 4608, rem = o % 4608;
      const int r = rem / 384, e = rem % 384;
      WdtT[o] = Wdt[i * 4608 + e * 12 + r];
    }
    return;
  }
  if (bid >= 294) {            // ---- wcvt part, float4-vectorized ----
    const int idx = ((bid - 294) * 256 + tid) * 4;   // segments all %4==0
    if (idx < 714240) {
      const float* src;
      if (idx < 442368) src = Win + idx;
      else if (idx < 663552) src = Wout + (idx - 442368);
      else src = Wx + (idx - 663552);
      const float4 tv = *(const float4*)src;
      bf16x4 o;
      o[0] = (__bf16)tv.x; o[1] = (__bf16)tv.y;
      o[2] = (__bf16)tv.z; o[3] = (__bf16)tv.w;
      *(bf16x4*)(Wb + idx) = o;
    }
    return;
  }

  const int r0 = (bid % 98) * 64;
  const int col0 = (bid / 98) * 64;
  const int b = r0 / 3136, l0 = r0 % 3136;
  const int lane = tid & 63, wv = tid >> 6;
  const int rh = wv >> 1, ch = wv & 1;
  const int lm = lane & 15, quad = lane >> 4;

#pragma unroll
  for (int it = 0; it < 6; ++it) {
    const int idx = tid + it * 256;
    const int c = idx >> 4, l4 = idx & 15;
    const float4 t = *(const float4*)(x + ((size_t)(b * 96 + c)) * 3136 + l0 + l4 * 4);
    As[(l4 * 4 + 0) * SAP + c] = (__bf16)t.x;
    As[(l4 * 4 + 1) * SAP + c] = (__bf16)t.y;
    As[(l4 * 4 + 2) * SAP + c] = (__bf16)t.z;
    As[(l4 * 4 + 3) * SAP + c] = (__bf16)t.w;
  }
#pragma unroll
  for (int it = 0; it < 6; ++it) {
    const int idx = tid + it * 256;
    const int wr = idx / 24, kc = (idx % 24) * 4;
    const float4 t = *(const float4*)(pw + (size_t)(col0 + wr) * 96 + kc);
    bf16x4 o;
    o[0] = (__bf16)t.x; o[1] = (__bf16)t.y; o[2] = (__bf16)t.z; o[3] = (__bf16)t.w;
    *(bf16x4*)(&Ws[wr * SAP + kc]) = o;
  }
  __syncthreads();

  f32x4 acc[2][2] = {};
#pragma unroll
  for (int ks = 0; ks < 3; ++ks) {
    const int kb = ks * 32 + quad * 8;
    bf16x8 a0 = *(const bf16x8*)(&As[(rh * 32 + lm) * SAP + kb]);
    bf16x8 a1 = *(const bf16x8*)(&As[(rh * 32 + 16 + lm) * SAP + kb]);
    bf16x8 b0 = *(const bf16x8*)(&Ws[(ch * 32 + lm) * SAP + kb]);
    bf16x8 b1 = *(const bf16x8*)(&Ws[(ch * 32 + 16 + lm) * SAP + kb]);
    acc[0][0] = __builtin_amdgcn_mfma_f32_16x16x32_bf16(a0, b0, acc[0][0], 0, 0, 0);
    acc[0][1] = __builtin_amdgcn_mfma_f32_16x16x32_bf16(a0, b1, acc[0][1], 0, 0, 0);
    acc[1][0] = __builtin_amdgcn_mfma_f32_16x16x32_bf16(a1, b0, acc[1][0], 0, 0, 0);
    acc[1][1] = __builtin_amdgcn_mfma_f32_16x16x32_bf16(a1, b1, acc[1][1], 0, 0, 0);
  }

#pragma unroll
  for (int ti = 0; ti < 2; ++ti)
#pragma unroll
    for (int tj = 0; tj < 2; ++tj) {
      const int gcol = col0 + ch * 32 + tj * 16 + lm;
      const float s = rsqrtf(bnv[gcol] + 1e-5f) * bng[gcol];
      const float sh = (pb[gcol] - bnm[gcol]) * s + bnb[gcol];
#pragma unroll
      for (int j = 0; j < 4; ++j) {
        const int grow = r0 + rh * 32 + ti * 16 + quad * 4 + j;
        v[(size_t)grow * 192 + gcol] = acc[ti][tj][j] * s + sh;
      }
    }
}

// ---------------- depthwise causal conv K=4 + silu, 8 outputs/thread -> xiB bf16 ----
__global__ __launch_bounds__(256) void k_conv(
    const float* __restrict__ xz, __bf16* __restrict__ xiB,
    const float* __restrict__ cw, const float* __restrict__ cb,
    int Lseq, int nthreads)
{
  const int idx = blockIdx.x * 256 + threadIdx.x;
  if (idx >= nthreads) return;
  const int e = idx % 384;
  const int seg = idx / 384;
  const int nseg = Lseq / 8;
  const int b = seg / nseg;
  const int l0 = (seg % nseg) * 8;
  const float4 w4 = *(const float4*)(cw + e * 4);
  const float bv = cb[e];
  float xv[11];
#pragma unroll
  for (int k = 0; k < 11; ++k) {
    const int l = l0 - 3 + k;
    xv[k] = (l >= 0) ? xz[(size_t)(b * Lseq + l) * 768 + e] : 0.f;
  }
#pragma unroll
  for (int j = 0; j < 8; ++j) {
    const float a = bv + xv[j] * w4.x + xv[j + 1] * w4.y + xv[j + 2] * w4.z + xv[j + 3] * w4.w;
    xiB[(size_t)(b * Lseq + l0 + j) * 384 + e] = (__bf16)siluf(a);
  }
}

// ---------------- xz GEMM (K=192, N=768): LN(A) @ Win^T + b, streaming W ---------
template <int AMODE>
__global__ __launch_bounds__(256, 4) void k_gemm_xz(
    const float* __restrict__ A, const __bf16* __restrict__ W,
    const float* __restrict__ bias, float* __restrict__ O,
    int M, const float* __restrict__ lng, const float* __restrict__ lnb)
{
  constexpr int SA = 200;
  __shared__ __bf16 As[64 * SA];
  __shared__ float lnS[384];
  const int tid = threadIdx.x;
  const int r0 = blockIdx.x * 64;
  const int col0 = blockIdx.y * 128;
  const int lane = tid & 63, wv = tid >> 6;
  const int rh = wv & 1, ch = wv >> 1;
  const int lm = lane & 15, quad = lane >> 4;

  if (tid < 192) { lnS[tid] = lng[tid]; lnS[192 + tid] = lnb[tid]; }
  __syncthreads();

  // ---- stage A: 4 lanes per row, LN fused, bf16 out ----
  {
    const int row = tid >> 2, part = tid & 3;
    const int gr = min(r0 + row, M - 1);
    const int cbase = part * 48;
    float4 tv[12];
    if constexpr (AMODE == 2) {
#pragma unroll
      for (int j = 0; j < 12; ++j)
        tv[j] = *(const float4*)(A + (size_t)gr * 192 + cbase + j * 4);
    } else {  // maxpool2 of v (B,3136,192); gr is pooled pixel index
      const int bb = gr / 784, l2 = gr % 784;
      const int h2 = l2 / 28, w2 = l2 % 28;
      const float* p0 = A + (size_t)(bb * 3136 + h2 * 112 + w2 * 2) * 192;
#pragma unroll
      for (int j = 0; j < 12; ++j) {
        const int cc = cbase + j * 4;
        const float4 a0 = *(const float4*)(p0 + cc);
        const float4 a1 = *(const float4*)(p0 + 192 + cc);
        const float4 a2 = *(const float4*)(p0 + 56 * 192 + cc);
        const float4 a3 = *(const float4*)(p0 + 57 * 192 + cc);
        tv[j].x = fmaxf(fmaxf(a0.x, a1.x), fmaxf(a2.x, a3.x));
        tv[j].y = fmaxf(fmaxf(a0.y, a1.y), fmaxf(a2.y, a3.y));
        tv[j].z = fmaxf(fmaxf(a0.z, a1.z), fmaxf(a2.z, a3.z));
        tv[j].w = fmaxf(fmaxf(a0.w, a1.w), fmaxf(a2.w, a3.w));
      }
    }
    float s = 0.f, sq = 0.f;
#pragma unroll
    for (int j = 0; j < 12; ++j) {
      s += tv[j].x + tv[j].y + tv[j].z + tv[j].w;
      sq += tv[j].x * tv[j].x + tv[j].y * tv[j].y + tv[j].z * tv[j].z + tv[j].w * tv[j].w;
    }
    s += __shfl_xor(s, 1); s += __shfl_xor(s, 2);
    sq += __shfl_xor(sq, 1); sq += __shfl_xor(sq, 2);
    const float mean = s * (1.f / 192.f);
    const float rstd = rsqrtf(sq * (1.f / 192.f) - mean * mean + 1e-5f);
#pragma unroll
    for (int j = 0; j < 12; ++j) {
      const int c = cbase + j * 4;
      bf16x4 o;
      o[0] = (__bf16)((tv[j].x - mean) * rstd * lnS[c + 0] + lnS[192 + c + 0]);
      o[1] = (__bf16)((tv[j].y - mean) * rstd * lnS[c + 1] + lnS[192 + c + 1]);
      o[2] = (__bf16)((tv[j].z - mean) * rstd * lnS[c + 2] + lnS[192 + c + 2]);
      o[3] = (__bf16)((tv[j].w - mean) * rstd * lnS[c + 3] + lnS[192 + c + 3]);
      *(bf16x4*)(&As[row * SA + c]) = o;
    }
  }
  __syncthreads();

  // ---- MFMA, B streamed from global ----
  f32x4 acc[2][4] = {};
#pragma unroll
  for (int ks = 0; ks < 6; ++ks) {
    const int kb = ks * 32 + quad * 8;
    bf16x8 a0 = *(const bf16x8*)(&As[(rh * 32 + lm) * SA + kb]);
    bf16x8 a1 = *(const bf16x8*)(&As[(rh * 32 + 16 + lm) * SA + kb]);
#pragma unroll
    for (int tj = 0; tj < 4; ++tj) {
      const int gw = col0 + ch * 64 + tj * 16 + lm;
      bf16x8 bfr = *(const bf16x8*)(W + (size_t)gw * 192 + kb);
      acc[0][tj] = __builtin_amdgcn_mfma_f32_16x16x32_bf16(a0, bfr, acc[0][tj], 0, 0, 0);
      acc[1][tj] = __builtin_amdgcn_mfma_f32_16x16x32_bf16(a1, bfr, acc[1][tj], 0, 0, 0);
    }
  }

  // ---- epilogue: write xz ----
#pragma unroll
  for (int ti = 0; ti < 2; ++ti)
#pragma unroll
    for (int tj = 0; tj < 4; ++tj) {
      const int gcol = col0 + ch * 64 + tj * 16 + lm;
      const float bv = bias[gcol];
#pragma unroll
      for (int j = 0; j < 4; ++j) {
        const int rowt = rh * 32 + ti * 16 + quad * 4 + j;
        const int grow = r0 + rowt;
        if (grow < M) O[(size_t)grow * 768 + gcol] = acc[ti][tj][j] + bv;
      }
    }
}

// ------- streaming-W small-N GEMM, 16-row x 64-col blocks, A-only LDS ----------
// Transposed outputs (RES_SKIP/OUT2) via LDS tile + float4-contiguous stores.
constexpr int EPI_G2 = 1, EPI_RES = 2, EPI_RES_SKIP = 3, EPI_OUT2 = 4;

template <int EPI>
__global__ __launch_bounds__(256) void k_gemm_s(
    const __bf16* __restrict__ Ab, const __bf16* __restrict__ W,
    const float* __restrict__ bias, float* __restrict__ O,
    int M, int K, int Nvalid,
    float* __restrict__ dtlbuf, float* __restrict__ bcbuf,
    float* __restrict__ oflt)
{
  constexpr int SA = 200;
  __shared__ __align__(16) char smem[16 * SA * 2];   // As (6400B) / tS (4224B)
  __bf16* As = (__bf16*)smem;
  __shared__ float dtlS[(EPI == EPI_G2) ? 16 * 12 : 1];
  const int tid = threadIdx.x;
  const int r0 = blockIdx.x * 16;
  const int col0 = blockIdx.y * 64;
  const int lane = tid & 63, wv = tid >> 6;
  const int ch = wv;
  const int lm = lane & 15, quad = lane >> 4;

  f32x4 acc = {};
  const int nkp = K / 192;
  for (int kp = 0; kp < nkp; ++kp) {
    if (kp) __syncthreads();
    {
      const int idx = tid;                 // 0..255
      const int row = idx / 24, kc = (idx % 24) * 8;
      const int gr = min(r0 + row, M - 1);
      if (row < 16)
        *(bf16x8*)(&As[row * SA + kc]) =
            *(const bf16x8*)(Ab + (size_t)gr * K + kp * 192 + kc);
      const int idx2 = tid + 256;
      if (idx2 < 384) {
        const int row2 = idx2 / 24, kc2 = (idx2 % 24) * 8;
        const int gr2 = min(r0 + row2, M - 1);
        *(bf16x8*)(&As[row2 * SA + kc2]) =
            *(const bf16x8*)(Ab + (size_t)gr2 * K + kp * 192 + kc2);
      }
    }
    __syncthreads();
#pragma unroll
    for (int ks = 0; ks < 6; ++ks) {
      const int kb = ks * 32 + quad * 8;
      bf16x8 a0 = *(const bf16x8*)(&As[lm * SA + kb]);
      const int gw = min(col0 + ch * 16 + lm, Nvalid - 1);  // clamp: cols >= Nvalid discarded
      bf16x8 bfr = *(const bf16x8*)(W + (size_t)gw * K + kp * 192 + kb);
      acc = __builtin_amdgcn_mfma_f32_16x16x32_bf16(a0, bfr, acc, 0, 0, 0);
    }
  }

  // ---- epilogue ----
  const int colt = ch * 16 + lm;
  if constexpr (EPI == EPI_G2) {
#pragma unroll
    for (int j = 0; j < 4; ++j) {
      const int rowt = quad * 4 + j;
      const int grow = r0 + rowt;
      const float val = acc[j];
      if (colt < 12) dtlS[rowt * 12 + colt] = val;
      else if (colt < 44 && grow < M)
        bcbuf[(size_t)grow * 32 + (colt - 12)] = val;
    }
    __syncthreads();
    if (tid < 192) {
      const int grow = r0 + tid / 12;
      if (grow < M) dtlbuf[(size_t)grow * 12 + tid % 12] = dtlS[tid];
    }
  } else {
    const int gcol = col0 + colt;
    const float bv = bias[gcol];
    float nv4[4];
#pragma unroll
    for (int j = 0; j < 4; ++j) {
      const int rowt = quad * 4 + j;
      const int grow = r0 + rowt;      // grid = M/16 exactly -> always < M
      const float val = acc[j] + bv;
      if constexpr (EPI == EPI_RES) {
        O[(size_t)grow * 192 + gcol] += val;
      } else if constexpr (EPI == EPI_RES_SKIP) {
        const float nvv = O[(size_t)grow * 192 + gcol] + val;
        O[(size_t)grow * 192 + gcol] = nvv;
        nv4[j] = nvv;
      } else {  // EPI_OUT2
        nv4[j] = val;
      }
    }
    if constexpr (EPI == EPI_RES_SKIP || EPI == EPI_OUT2) {
      float* tS = (float*)smem;           // [16][66] fp32 overlaying As
      __syncthreads();                    // all As reads done
#pragma unroll
      for (int j = 0; j < 4; ++j)
        tS[(quad * 4 + j) * 66 + colt] = nv4[j];
      __syncthreads();
      // coalesced transposed store: thread -> (gcol2 = tid>>2, 4 rows)
      constexpr int Lpix = (EPI == EPI_RES_SKIP) ? 3136 : 784;
      constexpr int strideB = (EPI == EPI_RES_SKIP) ? 602112 : 150528;
      const int c2 = tid >> 2, part = tid & 3;
      const int bb = r0 / Lpix;           // 16-row tile never straddles b
      const int l0 = r0 - bb * Lpix;
      float4 o4;
      o4.x = tS[(part * 4 + 0) * 66 + c2];
      o4.y = tS[(part * 4 + 1) * 66 + c2];
      o4.z = tS[(part * 4 + 2) * 66 + c2];
      o4.w = tS[(part * 4 + 3) * 66 + c2];
      *(float4*)(oflt + (size_t)bb * strideB + (size_t)(col0 + c2) * Lpix +
                 l0 + part * 4) = o4;
    }
  }
}

// ======== chunked selective scan: 1 LANE-PAIR = 1 channel, 8 states/thread ======
// dt-projection split across the pair (7 rows each); the partner's 7 dts come
// via register __shfl_xor(.,1) (R12). Wdt staged from pre-transposed WdtT
// (R15: fully coalesced staging, was 48B-stride scatter).
constexpr int SC_LC = 14;

__global__ __launch_bounds__(256) void k_scan1(
    const float* __restrict__ dtl, const __bf16* __restrict__ xi,
    const float* __restrict__ bc, const float* __restrict__ WdtT,
    const float* __restrict__ bdt, const float* __restrict__ A_log,
    float* __restrict__ DT, float* __restrict__ S, int Lseq, int NC)
{
  __shared__ float Bs[SC_LC * 16];
  __shared__ float dtlS[SC_LC * 12];
  __shared__ float wdtS[12 * 128];
  const int t = threadIdx.x;
  const int el = t >> 1, half = t & 1, n0h = half * 8;
  const int e0 = blockIdx.y * 128;
  const int e = e0 + el;
  const int c = blockIdx.x % NC;
  const int b = blockIdx.x / NC;
  const int rowbase = b * Lseq + c * SC_LC;

  if (t < SC_LC * 16)
    Bs[t] = bc[(size_t)(rowbase + (t >> 4)) * 32 + (t & 15)];
  if (t < SC_LC * 12)
    dtlS[t] = dtl[(size_t)(rowbase + t / 12) * 12 + t % 12];
  for (int idx = t; idx < 12 * 128; idx += 256) {
    const int r = idx >> 7, ee = idx & 127;
    wdtS[idx] = WdtT[r * 384 + e0 + ee];    // coalesced (WdtT is [12][384])
  }
  const float bdte = bdt[e];

  float An2[8];
  {
    const float4* a4 = (const float4*)(A_log + e * 16 + n0h);
    float4 t0 = a4[0], t1 = a4[1];
    float tmp[8] = {t0.x, t0.y, t0.z, t0.w, t1.x, t1.y, t1.z, t1.w};
#pragma unroll
    for (int n = 0; n < 8; ++n) An2[n] = -__expf(tmp[n]) * 1.44269504f;
  }
  __syncthreads();

  // 7 own dts in regs; partner's 7 via shfl (compile-time indices only)
  float dto[7];
  float dtp = 0.f;
#pragma unroll
  for (int j = 0; j < 7; ++j) {
    const int l = half * 7 + j;
    float a = bdte;
#pragma unroll
    for (int r = 0; r < 12; ++r) a += dtlS[l * 12 + r] * wdtS[r * 128 + el];
    dto[j] = softplusf(a);
    dtp += dto[j];
  }
  const float dtsum = dtp + __shfl_xor(dtp, 1);
  float dts_r[SC_LC];
#pragma unroll
  for (int j = 0; j < 7; ++j) {
    const float oth = __shfl_xor(dto[j], 1);
    dts_r[j]     = half ? oth : dto[j];
    dts_r[7 + j] = half ? dto[j] : oth;
  }

  float xall[SC_LC];
#pragma unroll
  for (int l = 0; l < SC_LC; ++l)
    xall[l] = (float)xi[(size_t)(rowbase + l) * 384 + e];

  float h[8];
#pragma unroll
  for (int n = 0; n < 8; ++n) h[n] = 0.f;
#pragma unroll
  for (int l = 0; l < SC_LC; ++l) {
    const float dtv = dts_r[l];
    const float u = dtv * xall[l];
    const float* Brow = &Bs[l * 16 + n0h];
#pragma unroll
    for (int n = 0; n < 8; ++n) {
      const float a = __builtin_amdgcn_exp2f(dtv * An2[n]);
      h[n] = a * h[n] + u * Brow[n];
    }
  }
  const size_t o = ((size_t)(b * NC + c) * 384 + e) * 16 + n0h;
  *(float4*)(S + o)     = make_float4(h[0], h[1], h[2], h[3]);
  *(float4*)(S + o + 4) = make_float4(h[4], h[5], h[6], h[7]);
  if (half == 0) DT[(size_t)(b * NC + c) * 384 + e] = dtsum;
}

// carry: prefix-fold chunk (dtsum,S) -> H0 in-place over S; depth-8 batches,
// software double-buffer (192 waves total -> ILP is all it has).
__global__ __launch_bounds__(256) void k_carry(
    const float* __restrict__ DT, float* __restrict__ SH,
    const float* __restrict__ A_log, int NC)
{
  const int tid = blockIdx.x * 256 + threadIdx.x;   // 12288
  const int b = tid / 6144, r = tid % 6144;         // r = e*16 + n
  const float An2 = -__expf(A_log[r]) * 1.44269504f;
  const size_t o = (size_t)b * NC * 6144 + r;
  const size_t od = (size_t)b * NC * 384 + (r >> 4);

  float sA[8], dA[8], sB[8], dB[8];
  auto LOAD = [&](float (&sv)[8], float (&dv)[8], int c0) {
#pragma unroll
    for (int k = 0; k < 8; ++k) {
      sv[k] = SH[o + (size_t)(c0 + k) * 6144];
      dv[k] = DT[od + (size_t)(c0 + k) * 384];
    }
  };
  float h = 0.f;
  auto COMP = [&](const float (&sv)[8], const float (&dv)[8], int c0) {
    float a[8];
#pragma unroll
    for (int k = 0; k < 8; ++k) a[k] = __builtin_amdgcn_exp2f(An2 * dv[k]);
#pragma unroll
    for (int k = 0; k < 8; ++k) {
      SH[o + (size_t)(c0 + k) * 6144] = h;
      h = a[k] * h + sv[k];
    }
  };

  LOAD(sA, dA, 0);
  for (int c0 = 0; c0 < NC; c0 += 16) {   // NC % 8 == 0 (224, 56)
    if (c0 + 8 < NC) LOAD(sB, dB, c0 + 8);
    COMP(sA, dA, c0);
    if (c0 + 8 < NC) {
      if (c0 + 16 < NC) LOAD(sA, dA, c0 + 16);
      COMP(sB, dB, c0 + 8);
    }
  }
}

// scan2: init from H0, recompute chunk with pair-split states, emit gated y
__global__ __launch_bounds__(256) void k_scan2(
    const float* __restrict__ dtl, const __bf16* __restrict__ xi,
    const float* __restrict__ bc, const float* __restrict__ xz,
    const float* __restrict__ WdtT, const float* __restrict__ bdt,
    const float* __restrict__ A_log, const float* __restrict__ Dskip,
    const float* __restrict__ H0, __bf16* __restrict__ y, int Lseq, int NC)
{
  __shared__ float BCs[SC_LC * 32];
  __shared__ float dtlS[SC_LC * 12];
  __shared__ float wdtS[12 * 128];
  const int t = threadIdx.x;
  const int el = t >> 1, half = t & 1, n0h = half * 8;
  const int e0 = blockIdx.y * 128;
  const int e = e0 + el;
  const int c = blockIdx.x % NC;
  const int b = blockIdx.x / NC;
  const int rowbase = b * Lseq + c * SC_LC;

  for (int idx = t; idx < SC_LC * 32; idx += 256)
    BCs[idx] = bc[(size_t)rowbase * 32 + idx];
  if (t < SC_LC * 12)
    dtlS[t] = dtl[(size_t)(rowbase + t / 12) * 12 + t % 12];
  for (int idx = t; idx < 12 * 128; idx += 256) {
    const int r = idx >> 7, ee = idx & 127;
    wdtS[idx] = WdtT[r * 384 + e0 + ee];    // coalesced
  }
  const float bdte = bdt[e];

  float An2[8];
  {
    const float4* a4 = (const float4*)(A_log + e * 16 + n0h);
    float4 t0 = a4[0], t1 = a4[1];
    float tmp[8] = {t0.x, t0.y, t0.z, t0.w, t1.x, t1.y, t1.z, t1.w};
#pragma unroll
    for (int n = 0; n < 8; ++n) An2[n] = -__expf(tmp[n]) * 1.44269504f;
  }
  float h[8];
  {
    const size_t o = ((size_t)(b * NC + c) * 384 + e) * 16 + n0h;
    const float4* h4 = (const float4*)(H0 + o);
    float4 t0 = h4[0], t1 = h4[1];
    h[0]=t0.x; h[1]=t0.y; h[2]=t0.z; h[3]=t0.w;
    h[4]=t1.x; h[5]=t1.y; h[6]=t1.z; h[7]=t1.w;
  }
  __syncthreads();

  float dto[7];
#pragma unroll
  for (int j = 0; j < 7; ++j) {
    const int l = half * 7 + j;
    float a = bdte;
#pragma unroll
    for (int r = 0; r < 12; ++r) a += dtlS[l * 12 + r] * wdtS[r * 128 + el];
    dto[j] = softplusf(a);
  }
  float dts_r[SC_LC];
#pragma unroll
  for (int j = 0; j < 7; ++j) {
    const float oth = __shfl_xor(dto[j], 1);
    dts_r[j]     = half ? oth : dto[j];
    dts_r[7 + j] = half ? dto[j] : oth;
  }
  const float Dse = Dskip[e];

  float xall[SC_LC], zall[SC_LC];
#pragma unroll
  for (int l = 0; l < SC_LC; ++l) {
    const size_t r = (size_t)(rowbase + l);
    xall[l] = (float)xi[r * 384 + e];
    zall[l] = xz[r * 768 + 384 + e];
  }

#pragma unroll
  for (int l = 0; l < SC_LC; ++l) {
    const float dtv = dts_r[l];
    const float xiv = xall[l];
    const float u = dtv * xiv;
    const float* Brow = &BCs[l * 32 + n0h];
    const float* Crow = &BCs[l * 32 + 16 + n0h];
    float yv = 0.f;
#pragma unroll
    for (int n = 0; n < 8; ++n) {
      const float a = __builtin_amdgcn_exp2f(dtv * An2[n]);
      h[n] = a * h[n] + u * Brow[n];
      yv += h[n] * Crow[n];
    }
    const float yt = yv + __shfl_xor(yv, 1);
    if (half == 0)
      y[(size_t)(rowbase + l) * 384 + e] = (__bf16)((yt + Dse * xiv) * siluf(zall[l]));
  }
}

extern "C" void kernel_launch(void* const* d_in, const int* in_sizes, int n_in,
                              void* d_out, int out_size, void* d_ws, size_t ws_size,
                              hipStream_t stream)
{
  const float* x    = (const float*)d_in[0];
  const float* pw   = (const float*)d_in[1];
  const float* pb   = (const float*)d_in[2];
  const float* bng  = (const float*)d_in[3];
  const float* bnb  = (const float*)d_in[4];
  const float* bnm  = (const float*)d_in[5];
  const float* bnv  = (const float*)d_in[6];
  const float* lng  = (const float*)d_in[7];
  const float* lnb  = (const float*)d_in[8];
  const float* Win  = (const float*)d_in[9];
  const float* b_in = (const float*)d_in[10];
  const float* cw   = (const float*)d_in[11];
  const float* cb   = (const float*)d_in[12];
  const float* Wx   = (const float*)d_in[13];
  const float* Wdt  = (const float*)d_in[14];
  const float* bdt  = (const float*)d_in[15];
  const float* Alog = (const float*)d_in[16];
  const float* Dsk  = (const float*)d_in[17];
  const float* Wout = (const float*)d_in[18];
  const float* bout = (const float*)d_in[19];

  float* wsf = (float*)d_ws;
  float* v    = wsf;                     // 1204224
  float* xz   = v + 1204224;             // 4816896
  float* dtlb = xz + 4816896;            // 75264
  float* bcb  = dtlb + 75264;            // 200704
  float* Sb   = bcb + 200704;            // 2752512 (NC up to 224)
  float* Pb   = Sb + 2752512;            // dtsum: 172032 used; WdtT in tail
  __bf16* xiB = (__bf16*)(Pb + 2752512); // 2408448 bf16
  __bf16* yB  = (__bf16*)(Pb + 2752512 + 1204224);   // 2408448 bf16
  __bf16* Wb  = (__bf16*)(Pb + 2752512 + 2408448);   // 714240 bf16
  float* WdtT = Pb + 524288;             // 13824 fp32 (3 x 12 x 384)

  float* out0 = (float*)d_out;
  float* out1 = out0 + 301056;

  k_proj_wcvt<<<1006, 256, 0, stream>>>(x, pw, pb, bng, bnb, bnm, bnv, v,
                                        Win, Wout, Wx, Wb, Wdt, WdtT);

  for (int i = 0; i < 3; ++i) {
    const int big = (i < 2) ? 1 : 0;
    const int Lseq = big ? 3136 : 784;
    const int M = 2 * Lseq;
    const int NC = Lseq / SC_LC;     // 224 big, 56 small
    const int MB = (M + 63) / 64;    // 98 big, 25 small
    const int MB16 = M / 16;         // 392 big, 98 small
    const float* lng_i = lng + i * 192;
    const float* lnb_i = lnb + i * 192;
    const float* bin_i = b_in + i * 768;
    const float* cw_i  = cw + i * 384 * 4;
    const float* cb_i  = cb + i * 384;
    const float* WdtT_i = WdtT + i * 4608;
    const float* bdt_i = bdt + i * 384;
    const float* Al_i  = Alog + i * 384 * 16;
    const float* Ds_i  = Dsk + i * 384;
    const float* bo_i  = bout + i * 192;
    const __bf16* Winb_i  = Wb + i * 147456;
    const __bf16* Woutb_i = Wb + 442368 + i * 73728;
    const __bf16* Wxb_i   = Wb + 663552 + i * 16896;

    // xz = LN(src) @ Win^T + b_in  (streaming-W, 4 blk/CU)
    if (big)
      k_gemm_xz<2><<<dim3(MB, 6), 256, 0, stream>>>(
          v, Winb_i, bin_i, xz, M, lng_i, lnb_i);
    else
      k_gemm_xz<3><<<dim3(MB, 6), 256, 0, stream>>>(
          v, Winb_i, bin_i, xz, M, lng_i, lnb_i);
    // depthwise conv + silu -> xiB bf16
    k_conv<<<(M * 384 / 8 + 255) / 256, 256, 0, stream>>>(
        xz, xiB, cw_i, cb_i, Lseq, M * 384 / 8);
    // proj (44 cols): writes dtl (M x 12) + bc (M x 32); 16-row streaming blocks
    k_gemm_s<EPI_G2><<<dim3(MB16, 1), 256, 0, stream>>>(
        xiB, Wxb_i, nullptr, nullptr, M, 384, 44, dtlb, bcb, nullptr);
    k_scan1<<<dim3(2 * NC, 3), 256, 0, stream>>>(
        dtlb, xiB, bcb, WdtT_i, bdt_i, Al_i, Pb, Sb, Lseq, NC);
    k_carry<<<48, 256, 0, stream>>>(Pb, Sb, Al_i, NC);
    k_scan2<<<dim3(2 * NC, 3), 256, 0, stream>>>(
        dtlb, xiB, bcb, xz, WdtT_i, bdt_i, Al_i, Ds_i, Sb, yB, Lseq, NC);
    if (i == 0)
      k_gemm_s<EPI_RES><<<dim3(MB16, 3), 256, 0, stream>>>(
          yB, Woutb_i, bo_i, v, M, 384, 192, nullptr, nullptr, nullptr);
    else if (i == 1)
      k_gemm_s<EPI_RES_SKIP><<<dim3(MB16, 3), 256, 0, stream>>>(
          yB, Woutb_i, bo_i, v, M, 384, 192, nullptr, nullptr, out1);
    else
      k_gemm_s<EPI_OUT2><<<dim3(MB16, 3), 256, 0, stream>>>(
          yB, Woutb_i, bo_i, v, M, 384, 192, nullptr, nullptr, out0);
  }
}

// Round 16
// 319.785 us; speedup vs baseline: 1.0780x; 1.0173x over previous
//
#include <hip/hip_runtime.h>

typedef __attribute__((ext_vector_type(8))) __bf16 bf16x8;
typedef __attribute__((ext_vector_type(4))) __bf16 bf16x4;
typedef __attribute__((ext_vector_type(4))) float f32x4;

#define DEV static __device__ __forceinline__

DEV float fast_rcp(float x) { return __builtin_amdgcn_rcpf(x); }
DEV float sigm(float x) { return fast_rcp(1.f + __expf(-x)); }
DEV float siluf(float x) { return x * sigm(x); }
DEV float softplusf(float x) { return x > 20.f ? x : __logf(1.f + __expf(x)); }

// Ledger: R3 no in-kernel grid sync (non-coherent per-XCD L2). R5/R9/R11:
// fusion must DELETE work, not move it into latency-bound consumers. R6/R7:
// stream W from L2 for small-N GEMMs. R8: pair-split scan (TLP). R10:
// LDS-coalesced transposed stores. R12: dts via register shfl. R13 (reverted):
// bf16 demotion -- latency-bound, not traffic-bound. R15: WdtT pre-transpose.
// R16: float4-vectorized scan staging (dtl/bc/wdt contiguous sources).

// ---------------- proj (96->192) MFMA GEMM + BN  ||  weight fp32->bf16 convert ----
__global__ __launch_bounds__(256) void k_proj_wcvt(
    const float* __restrict__ x, const float* __restrict__ pw,
    const float* __restrict__ pb, const float* __restrict__ bng,
    const float* __restrict__ bnb, const float* __restrict__ bnm,
    const float* __restrict__ bnv, float* __restrict__ v,
    const float* __restrict__ Win, const float* __restrict__ Wout,
    const float* __restrict__ Wx, __bf16* __restrict__ Wb,
    const float* __restrict__ Wdt, float* __restrict__ WdtT)
{
  constexpr int SAP = 104;
  __shared__ __bf16 As[64 * SAP];
  __shared__ __bf16 Ws[64 * SAP];
  const int tid = threadIdx.x;
  const int bid = blockIdx.x;

  if (bid >= 992) {            // ---- Wdt transpose: (3,384,12) -> (3,12,384) ----
    const int o = (bid - 992) * 256 + tid;
    if (o < 13824) {
      const int i = o / 4608, rem = o % 4608;
      const int r = rem / 384, e = rem % 384;
      WdtT[o] = Wdt[i * 4608 + e * 12 + r];
    }
    return;
  }
  if (bid >= 294) {            // ---- wcvt part, float4-vectorized ----
    const int idx = ((bid - 294) * 256 + tid) * 4;   // segments all %4==0
    if (idx < 714240) {
      const float* src;
      if (idx < 442368) src = Win + idx;
      else if (idx < 663552) src = Wout + (idx - 442368);
      else src = Wx + (idx - 663552);
      const float4 tv = *(const float4*)src;
      bf16x4 o;
      o[0] = (__bf16)tv.x; o[1] = (__bf16)tv.y;
      o[2] = (__bf16)tv.z; o[3] = (__bf16)tv.w;
      *(bf16x4*)(Wb + idx) = o;
    }
    return;
  }

  const int r0 = (bid % 98) * 64;
  const int col0 = (bid / 98) * 64;
  const int b = r0 / 3136, l0 = r0 % 3136;
  const int lane = tid & 63, wv = tid >> 6;
  const int rh = wv >> 1, ch = wv & 1;
  const int lm = lane & 15, quad = lane >> 4;

#pragma unroll
  for (int it = 0; it < 6; ++it) {
    const int idx = tid + it * 256;
    const int c = idx >> 4, l4 = idx & 15;
    const float4 t = *(const float4*)(x + ((size_t)(b * 96 + c)) * 3136 + l0 + l4 * 4);
    As[(l4 * 4 + 0) * SAP + c] = (__bf16)t.x;
    As[(l4 * 4 + 1) * SAP + c] = (__bf16)t.y;
    As[(l4 * 4 + 2) * SAP + c] = (__bf16)t.z;
    As[(l4 * 4 + 3) * SAP + c] = (__bf16)t.w;
  }
#pragma unroll
  for (int it = 0; it < 6; ++it) {
    const int idx = tid + it * 256;
    const int wr = idx / 24, kc = (idx % 24) * 4;
    const float4 t = *(const float4*)(pw + (size_t)(col0 + wr) * 96 + kc);
    bf16x4 o;
    o[0] = (__bf16)t.x; o[1] = (__bf16)t.y; o[2] = (__bf16)t.z; o[3] = (__bf16)t.w;
    *(bf16x4*)(&Ws[wr * SAP + kc]) = o;
  }
  __syncthreads();

  f32x4 acc[2][2] = {};
#pragma unroll
  for (int ks = 0; ks < 3; ++ks) {
    const int kb = ks * 32 + quad * 8;
    bf16x8 a0 = *(const bf16x8*)(&As[(rh * 32 + lm) * SAP + kb]);
    bf16x8 a1 = *(const bf16x8*)(&As[(rh * 32 + 16 + lm) * SAP + kb]);
    bf16x8 b0 = *(const bf16x8*)(&Ws[(ch * 32 + lm) * SAP + kb]);
    bf16x8 b1 = *(const bf16x8*)(&Ws[(ch * 32 + 16 + lm) * SAP + kb]);
    acc[0][0] = __builtin_amdgcn_mfma_f32_16x16x32_bf16(a0, b0, acc[0][0], 0, 0, 0);
    acc[0][1] = __builtin_amdgcn_mfma_f32_16x16x32_bf16(a0, b1, acc[0][1], 0, 0, 0);
    acc[1][0] = __builtin_amdgcn_mfma_f32_16x16x32_bf16(a1, b0, acc[1][0], 0, 0, 0);
    acc[1][1] = __builtin_amdgcn_mfma_f32_16x16x32_bf16(a1, b1, acc[1][1], 0, 0, 0);
  }

#pragma unroll
  for (int ti = 0; ti < 2; ++ti)
#pragma unroll
    for (int tj = 0; tj < 2; ++tj) {
      const int gcol = col0 + ch * 32 + tj * 16 + lm;
      const float s = rsqrtf(bnv[gcol] + 1e-5f) * bng[gcol];
      const float sh = (pb[gcol] - bnm[gcol]) * s + bnb[gcol];
#pragma unroll
      for (int j = 0; j < 4; ++j) {
        const int grow = r0 + rh * 32 + ti * 16 + quad * 4 + j;
        v[(size_t)grow * 192 + gcol] = acc[ti][tj][j] * s + sh;
      }
    }
}

// ---------------- depthwise causal conv K=4 + silu, 8 outputs/thread -> xiB bf16 ----
__global__ __launch_bounds__(256) void k_conv(
    const float* __restrict__ xz, __bf16* __restrict__ xiB,
    const float* __restrict__ cw, const float* __restrict__ cb,
    int Lseq, int nthreads)
{
  const int idx = blockIdx.x * 256 + threadIdx.x;
  if (idx >= nthreads) return;
  const int e = idx % 384;
  const int seg = idx / 384;
  const int nseg = Lseq / 8;
  const int b = seg / nseg;
  const int l0 = (seg % nseg) * 8;
  const float4 w4 = *(const float4*)(cw + e * 4);
  const float bv = cb[e];
  float xv[11];
#pragma unroll
  for (int k = 0; k < 11; ++k) {
    const int l = l0 - 3 + k;
    xv[k] = (l >= 0) ? xz[(size_t)(b * Lseq + l) * 768 + e] : 0.f;
  }
#pragma unroll
  for (int j = 0; j < 8; ++j) {
    const float a = bv + xv[j] * w4.x + xv[j + 1] * w4.y + xv[j + 2] * w4.z + xv[j + 3] * w4.w;
    xiB[(size_t)(b * Lseq + l0 + j) * 384 + e] = (__bf16)siluf(a);
  }
}

// ---------------- xz GEMM (K=192, N=768): LN(A) @ Win^T + b, streaming W ---------
template <int AMODE>
__global__ __launch_bounds__(256, 4) void k_gemm_xz(
    const float* __restrict__ A, const __bf16* __restrict__ W,
    const float* __restrict__ bias, float* __restrict__ O,
    int M, const float* __restrict__ lng, const float* __restrict__ lnb)
{
  constexpr int SA = 200;
  __shared__ __bf16 As[64 * SA];
  __shared__ float lnS[384];
  const int tid = threadIdx.x;
  const int r0 = blockIdx.x * 64;
  const int col0 = blockIdx.y * 128;
  const int lane = tid & 63, wv = tid >> 6;
  const int rh = wv & 1, ch = wv >> 1;
  const int lm = lane & 15, quad = lane >> 4;

  if (tid < 192) { lnS[tid] = lng[tid]; lnS[192 + tid] = lnb[tid]; }
  __syncthreads();

  // ---- stage A: 4 lanes per row, LN fused, bf16 out ----
  {
    const int row = tid >> 2, part = tid & 3;
    const int gr = min(r0 + row, M - 1);
    const int cbase = part * 48;
    float4 tv[12];
    if constexpr (AMODE == 2) {
#pragma unroll
      for (int j = 0; j < 12; ++j)
        tv[j] = *(const float4*)(A + (size_t)gr * 192 + cbase + j * 4);
    } else {  // maxpool2 of v (B,3136,192); gr is pooled pixel index
      const int bb = gr / 784, l2 = gr % 784;
      const int h2 = l2 / 28, w2 = l2 % 28;
      const float* p0 = A + (size_t)(bb * 3136 + h2 * 112 + w2 * 2) * 192;
#pragma unroll
      for (int j = 0; j < 12; ++j) {
        const int cc = cbase + j * 4;
        const float4 a0 = *(const float4*)(p0 + cc);
        const float4 a1 = *(const float4*)(p0 + 192 + cc);
        const float4 a2 = *(const float4*)(p0 + 56 * 192 + cc);
        const float4 a3 = *(const float4*)(p0 + 57 * 192 + cc);
        tv[j].x = fmaxf(fmaxf(a0.x, a1.x), fmaxf(a2.x, a3.x));
        tv[j].y = fmaxf(fmaxf(a0.y, a1.y), fmaxf(a2.y, a3.y));
        tv[j].z = fmaxf(fmaxf(a0.z, a1.z), fmaxf(a2.z, a3.z));
        tv[j].w = fmaxf(fmaxf(a0.w, a1.w), fmaxf(a2.w, a3.w));
      }
    }
    float s = 0.f, sq = 0.f;
#pragma unroll
    for (int j = 0; j < 12; ++j) {
      s += tv[j].x + tv[j].y + tv[j].z + tv[j].w;
      sq += tv[j].x * tv[j].x + tv[j].y * tv[j].y + tv[j].z * tv[j].z + tv[j].w * tv[j].w;
    }
    s += __shfl_xor(s, 1); s += __shfl_xor(s, 2);
    sq += __shfl_xor(sq, 1); sq += __shfl_xor(sq, 2);
    const float mean = s * (1.f / 192.f);
    const float rstd = rsqrtf(sq * (1.f / 192.f) - mean * mean + 1e-5f);
#pragma unroll
    for (int j = 0; j < 12; ++j) {
      const int c = cbase + j * 4;
      bf16x4 o;
      o[0] = (__bf16)((tv[j].x - mean) * rstd * lnS[c + 0] + lnS[192 + c + 0]);
      o[1] = (__bf16)((tv[j].y - mean) * rstd * lnS[c + 1] + lnS[192 + c + 1]);
      o[2] = (__bf16)((tv[j].z - mean) * rstd * lnS[c + 2] + lnS[192 + c + 2]);
      o[3] = (__bf16)((tv[j].w - mean) * rstd * lnS[c + 3] + lnS[192 + c + 3]);
      *(bf16x4*)(&As[row * SA + c]) = o;
    }
  }
  __syncthreads();

  // ---- MFMA, B streamed from global ----
  f32x4 acc[2][4] = {};
#pragma unroll
  for (int ks = 0; ks < 6; ++ks) {
    const int kb = ks * 32 + quad * 8;
    bf16x8 a0 = *(const bf16x8*)(&As[(rh * 32 + lm) * SA + kb]);
    bf16x8 a1 = *(const bf16x8*)(&As[(rh * 32 + 16 + lm) * SA + kb]);
#pragma unroll
    for (int tj = 0; tj < 4; ++tj) {
      const int gw = col0 + ch * 64 + tj * 16 + lm;
      bf16x8 bfr = *(const bf16x8*)(W + (size_t)gw * 192 + kb);
      acc[0][tj] = __builtin_amdgcn_mfma_f32_16x16x32_bf16(a0, bfr, acc[0][tj], 0, 0, 0);
      acc[1][tj] = __builtin_amdgcn_mfma_f32_16x16x32_bf16(a1, bfr, acc[1][tj], 0, 0, 0);
    }
  }

  // ---- epilogue: write xz ----
#pragma unroll
  for (int ti = 0; ti < 2; ++ti)
#pragma unroll
    for (int tj = 0; tj < 4; ++tj) {
      const int gcol = col0 + ch * 64 + tj * 16 + lm;
      const float bv = bias[gcol];
#pragma unroll
      for (int j = 0; j < 4; ++j) {
        const int rowt = rh * 32 + ti * 16 + quad * 4 + j;
        const int grow = r0 + rowt;
        if (grow < M) O[(size_t)grow * 768 + gcol] = acc[ti][tj][j] + bv;
      }
    }
}

// ------- streaming-W small-N GEMM, 16-row x 64-col blocks, A-only LDS ----------
// Transposed outputs (RES_SKIP/OUT2) via LDS tile + float4-contiguous stores.
constexpr int EPI_G2 = 1, EPI_RES = 2, EPI_RES_SKIP = 3, EPI_OUT2 = 4;

template <int EPI>
__global__ __launch_bounds__(256) void k_gemm_s(
    const __bf16* __restrict__ Ab, const __bf16* __restrict__ W,
    const float* __restrict__ bias, float* __restrict__ O,
    int M, int K, int Nvalid,
    float* __restrict__ dtlbuf, float* __restrict__ bcbuf,
    float* __restrict__ oflt)
{
  constexpr int SA = 200;
  __shared__ __align__(16) char smem[16 * SA * 2];   // As (6400B) / tS (4224B)
  __bf16* As = (__bf16*)smem;
  __shared__ float dtlS[(EPI == EPI_G2) ? 16 * 12 : 1];
  const int tid = threadIdx.x;
  const int r0 = blockIdx.x * 16;
  const int col0 = blockIdx.y * 64;
  const int lane = tid & 63, wv = tid >> 6;
  const int ch = wv;
  const int lm = lane & 15, quad = lane >> 4;

  f32x4 acc = {};
  const int nkp = K / 192;
  for (int kp = 0; kp < nkp; ++kp) {
    if (kp) __syncthreads();
    {
      const int idx = tid;                 // 0..255
      const int row = idx / 24, kc = (idx % 24) * 8;
      const int gr = min(r0 + row, M - 1);
      if (row < 16)
        *(bf16x8*)(&As[row * SA + kc]) =
            *(const bf16x8*)(Ab + (size_t)gr * K + kp * 192 + kc);
      const int idx2 = tid + 256;
      if (idx2 < 384) {
        const int row2 = idx2 / 24, kc2 = (idx2 % 24) * 8;
        const int gr2 = min(r0 + row2, M - 1);
        *(bf16x8*)(&As[row2 * SA + kc2]) =
            *(const bf16x8*)(Ab + (size_t)gr2 * K + kp * 192 + kc2);
      }
    }
    __syncthreads();
#pragma unroll
    for (int ks = 0; ks < 6; ++ks) {
      const int kb = ks * 32 + quad * 8;
      bf16x8 a0 = *(const bf16x8*)(&As[lm * SA + kb]);
      const int gw = min(col0 + ch * 16 + lm, Nvalid - 1);  // clamp: cols >= Nvalid discarded
      bf16x8 bfr = *(const bf16x8*)(W + (size_t)gw * K + kp * 192 + kb);
      acc = __builtin_amdgcn_mfma_f32_16x16x32_bf16(a0, bfr, acc, 0, 0, 0);
    }
  }

  // ---- epilogue ----
  const int colt = ch * 16 + lm;
  if constexpr (EPI == EPI_G2) {
#pragma unroll
    for (int j = 0; j < 4; ++j) {
      const int rowt = quad * 4 + j;
      const int grow = r0 + rowt;
      const float val = acc[j];
      if (colt < 12) dtlS[rowt * 12 + colt] = val;
      else if (colt < 44 && grow < M)
        bcbuf[(size_t)grow * 32 + (colt - 12)] = val;
    }
    __syncthreads();
    if (tid < 192) {
      const int grow = r0 + tid / 12;
      if (grow < M) dtlbuf[(size_t)grow * 12 + tid % 12] = dtlS[tid];
    }
  } else {
    const int gcol = col0 + colt;
    const float bv = bias[gcol];
    float nv4[4];
#pragma unroll
    for (int j = 0; j < 4; ++j) {
      const int rowt = quad * 4 + j;
      const int grow = r0 + rowt;      // grid = M/16 exactly -> always < M
      const float val = acc[j] + bv;
      if constexpr (EPI == EPI_RES) {
        O[(size_t)grow * 192 + gcol] += val;
      } else if constexpr (EPI == EPI_RES_SKIP) {
        const float nvv = O[(size_t)grow * 192 + gcol] + val;
        O[(size_t)grow * 192 + gcol] = nvv;
        nv4[j] = nvv;
      } else {  // EPI_OUT2
        nv4[j] = val;
      }
    }
    if constexpr (EPI == EPI_RES_SKIP || EPI == EPI_OUT2) {
      float* tS = (float*)smem;           // [16][66] fp32 overlaying As
      __syncthreads();                    // all As reads done
#pragma unroll
      for (int j = 0; j < 4; ++j)
        tS[(quad * 4 + j) * 66 + colt] = nv4[j];
      __syncthreads();
      // coalesced transposed store: thread -> (gcol2 = tid>>2, 4 rows)
      constexpr int Lpix = (EPI == EPI_RES_SKIP) ? 3136 : 784;
      constexpr int strideB = (EPI == EPI_RES_SKIP) ? 602112 : 150528;
      const int c2 = tid >> 2, part = tid & 3;
      const int bb = r0 / Lpix;           // 16-row tile never straddles b
      const int l0 = r0 - bb * Lpix;
      float4 o4;
      o4.x = tS[(part * 4 + 0) * 66 + c2];
      o4.y = tS[(part * 4 + 1) * 66 + c2];
      o4.z = tS[(part * 4 + 2) * 66 + c2];
      o4.w = tS[(part * 4 + 3) * 66 + c2];
      *(float4*)(oflt + (size_t)bb * strideB + (size_t)(col0 + c2) * Lpix +
                 l0 + part * 4) = o4;
    }
  }
}

// ======== chunked selective scan: 1 LANE-PAIR = 1 channel, 8 states/thread ======
// dt-projection split across the pair (7 rows each); partner's dts via register
// __shfl_xor (R12). WdtT staging coalesced (R15) + float4 staging (R16).
constexpr int SC_LC = 14;

__global__ __launch_bounds__(256) void k_scan1(
    const float* __restrict__ dtl, const __bf16* __restrict__ xi,
    const float* __restrict__ bc, const float* __restrict__ WdtT,
    const float* __restrict__ bdt, const float* __restrict__ A_log,
    float* __restrict__ DT, float* __restrict__ S, int Lseq, int NC)
{
  __shared__ float Bs[SC_LC * 16];
  __shared__ float dtlS[SC_LC * 12];
  __shared__ float wdtS[12 * 128];
  const int t = threadIdx.x;
  const int el = t >> 1, half = t & 1, n0h = half * 8;
  const int e0 = blockIdx.y * 128;
  const int e = e0 + el;
  const int c = blockIdx.x % NC;
  const int b = blockIdx.x / NC;
  const int rowbase = b * Lseq + c * SC_LC;

  if (t < 56) {                         // Bs: 14 rows x 16 floats, float4
    const int row = t >> 2, q4 = (t & 3) * 4;
    *(float4*)(&Bs[row * 16 + q4]) =
        *(const float4*)(bc + (size_t)(rowbase + row) * 32 + q4);
  }
  if (t >= 64 && t < 106) {             // dtlS: 168 contiguous floats, float4
    const int j = t - 64;
    *(float4*)(&dtlS[j * 4]) = *(const float4*)(dtl + (size_t)rowbase * 12 + j * 4);
  }
  for (int idx = t; idx < 384; idx += 256) {  // wdtS: 12 x 128, float4 rows
    const int r = idx >> 5, e4 = (idx & 31) * 4;
    *(float4*)(&wdtS[r * 128 + e4]) = *(const float4*)(&WdtT[r * 384 + e0 + e4]);
  }
  const float bdte = bdt[e];

  float An2[8];
  {
    const float4* a4 = (const float4*)(A_log + e * 16 + n0h);
    float4 t0 = a4[0], t1 = a4[1];
    float tmp[8] = {t0.x, t0.y, t0.z, t0.w, t1.x, t1.y, t1.z, t1.w};
#pragma unroll
    for (int n = 0; n < 8; ++n) An2[n] = -__expf(tmp[n]) * 1.44269504f;
  }
  __syncthreads();

  // 7 own dts in regs; partner's 7 via shfl (compile-time indices only)
  float dto[7];
  float dtp = 0.f;
#pragma unroll
  for (int j = 0; j < 7; ++j) {
    const int l = half * 7 + j;
    float a = bdte;
#pragma unroll
    for (int r = 0; r < 12; ++r) a += dtlS[l * 12 + r] * wdtS[r * 128 + el];
    dto[j] = softplusf(a);
    dtp += dto[j];
  }
  const float dtsum = dtp + __shfl_xor(dtp, 1);
  float dts_r[SC_LC];
#pragma unroll
  for (int j = 0; j < 7; ++j) {
    const float oth = __shfl_xor(dto[j], 1);
    dts_r[j]     = half ? oth : dto[j];
    dts_r[7 + j] = half ? dto[j] : oth;
  }

  float xall[SC_LC];
#pragma unroll
  for (int l = 0; l < SC_LC; ++l)
    xall[l] = (float)xi[(size_t)(rowbase + l) * 384 + e];

  float h[8];
#pragma unroll
  for (int n = 0; n < 8; ++n) h[n] = 0.f;
#pragma unroll
  for (int l = 0; l < SC_LC; ++l) {
    const float dtv = dts_r[l];
    const float u = dtv * xall[l];
    const float* Brow = &Bs[l * 16 + n0h];
#pragma unroll
    for (int n = 0; n < 8; ++n) {
      const float a = __builtin_amdgcn_exp2f(dtv * An2[n]);
      h[n] = a * h[n] + u * Brow[n];
    }
  }
  const size_t o = ((size_t)(b * NC + c) * 384 + e) * 16 + n0h;
  *(float4*)(S + o)     = make_float4(h[0], h[1], h[2], h[3]);
  *(float4*)(S + o + 4) = make_float4(h[4], h[5], h[6], h[7]);
  if (half == 0) DT[(size_t)(b * NC + c) * 384 + e] = dtsum;
}

// carry: prefix-fold chunk (dtsum,S) -> H0 in-place over S; depth-8 batches,
// software double-buffer (192 waves total -> ILP is all it has).
__global__ __launch_bounds__(256) void k_carry(
    const float* __restrict__ DT, float* __restrict__ SH,
    const float* __restrict__ A_log, int NC)
{
  const int tid = blockIdx.x * 256 + threadIdx.x;   // 12288
  const int b = tid / 6144, r = tid % 6144;         // r = e*16 + n
  const float An2 = -__expf(A_log[r]) * 1.44269504f;
  const size_t o = (size_t)b * NC * 6144 + r;
  const size_t od = (size_t)b * NC * 384 + (r >> 4);

  float sA[8], dA[8], sB[8], dB[8];
  auto LOAD = [&](float (&sv)[8], float (&dv)[8], int c0) {
#pragma unroll
    for (int k = 0; k < 8; ++k) {
      sv[k] = SH[o + (size_t)(c0 + k) * 6144];
      dv[k] = DT[od + (size_t)(c0 + k) * 384];
    }
  };
  float h = 0.f;
  auto COMP = [&](const float (&sv)[8], const float (&dv)[8], int c0) {
    float a[8];
#pragma unroll
    for (int k = 0; k < 8; ++k) a[k] = __builtin_amdgcn_exp2f(An2 * dv[k]);
#pragma unroll
    for (int k = 0; k < 8; ++k) {
      SH[o + (size_t)(c0 + k) * 6144] = h;
      h = a[k] * h + sv[k];
    }
  };

  LOAD(sA, dA, 0);
  for (int c0 = 0; c0 < NC; c0 += 16) {   // NC % 8 == 0 (224, 56)
    if (c0 + 8 < NC) LOAD(sB, dB, c0 + 8);
    COMP(sA, dA, c0);
    if (c0 + 8 < NC) {
      if (c0 + 16 < NC) LOAD(sA, dA, c0 + 16);
      COMP(sB, dB, c0 + 8);
    }
  }
}

// scan2: init from H0, recompute chunk with pair-split states, emit gated y
__global__ __launch_bounds__(256) void k_scan2(
    const float* __restrict__ dtl, const __bf16* __restrict__ xi,
    const float* __restrict__ bc, const float* __restrict__ xz,
    const float* __restrict__ WdtT, const float* __restrict__ bdt,
    const float* __restrict__ A_log, const float* __restrict__ Dskip,
    const float* __restrict__ H0, __bf16* __restrict__ y, int Lseq, int NC)
{
  __shared__ float BCs[SC_LC * 32];
  __shared__ float dtlS[SC_LC * 12];
  __shared__ float wdtS[12 * 128];
  const int t = threadIdx.x;
  const int el = t >> 1, half = t & 1, n0h = half * 8;
  const int e0 = blockIdx.y * 128;
  const int e = e0 + el;
  const int c = blockIdx.x % NC;
  const int b = blockIdx.x / NC;
  const int rowbase = b * Lseq + c * SC_LC;

  if (t < 112) {                        // BCs: 448 contiguous floats, float4
    *(float4*)(&BCs[t * 4]) = *(const float4*)(bc + (size_t)rowbase * 32 + t * 4);
  }
  if (t >= 128 && t < 170) {            // dtlS: 168 contiguous floats, float4
    const int j = t - 128;
    *(float4*)(&dtlS[j * 4]) = *(const float4*)(dtl + (size_t)rowbase * 12 + j * 4);
  }
  for (int idx = t; idx < 384; idx += 256) {  // wdtS: 12 x 128, float4 rows
    const int r = idx >> 5, e4 = (idx & 31) * 4;
    *(float4*)(&wdtS[r * 128 + e4]) = *(const float4*)(&WdtT[r * 384 + e0 + e4]);
  }
  const float bdte = bdt[e];

  float An2[8];
  {
    const float4* a4 = (const float4*)(A_log + e * 16 + n0h);
    float4 t0 = a4[0], t1 = a4[1];
    float tmp[8] = {t0.x, t0.y, t0.z, t0.w, t1.x, t1.y, t1.z, t1.w};
#pragma unroll
    for (int n = 0; n < 8; ++n) An2[n] = -__expf(tmp[n]) * 1.44269504f;
  }
  float h[8];
  {
    const size_t o = ((size_t)(b * NC + c) * 384 + e) * 16 + n0h;
    const float4* h4 = (const float4*)(H0 + o);
    float4 t0 = h4[0], t1 = h4[1];
    h[0]=t0.x; h[1]=t0.y; h[2]=t0.z; h[3]=t0.w;
    h[4]=t1.x; h[5]=t1.y; h[6]=t1.z; h[7]=t1.w;
  }
  __syncthreads();

  float dto[7];
#pragma unroll
  for (int j = 0; j < 7; ++j) {
    const int l = half * 7 + j;
    float a = bdte;
#pragma unroll
    for (int r = 0; r < 12; ++r) a += dtlS[l * 12 + r] * wdtS[r * 128 + el];
    dto[j] = softplusf(a);
  }
  float dts_r[SC_LC];
#pragma unroll
  for (int j = 0; j < 7; ++j) {
    const float oth = __shfl_xor(dto[j], 1);
    dts_r[j]     = half ? oth : dto[j];
    dts_r[7 + j] = half ? dto[j] : oth;
  }
  const float Dse = Dskip[e];

  float xall[SC_LC], zall[SC_LC];
#pragma unroll
  for (int l = 0; l < SC_LC; ++l) {
    const size_t r = (size_t)(rowbase + l);
    xall[l] = (float)xi[r * 384 + e];
    zall[l] = xz[r * 768 + 384 + e];
  }

#pragma unroll
  for (int l = 0; l < SC_LC; ++l) {
    const float dtv = dts_r[l];
    const float xiv = xall[l];
    const float u = dtv * xiv;
    const float* Brow = &BCs[l * 32 + n0h];
    const float* Crow = &BCs[l * 32 + 16 + n0h];
    float yv = 0.f;
#pragma unroll
    for (int n = 0; n < 8; ++n) {
      const float a = __builtin_amdgcn_exp2f(dtv * An2[n]);
      h[n] = a * h[n] + u * Brow[n];
      yv += h[n] * Crow[n];
    }
    const float yt = yv + __shfl_xor(yv, 1);
    if (half == 0)
      y[(size_t)(rowbase + l) * 384 + e] = (__bf16)((yt + Dse * xiv) * siluf(zall[l]));
  }
}

extern "C" void kernel_launch(void* const* d_in, const int* in_sizes, int n_in,
                              void* d_out, int out_size, void* d_ws, size_t ws_size,
                              hipStream_t stream)
{
  const float* x    = (const float*)d_in[0];
  const float* pw   = (const float*)d_in[1];
  const float* pb   = (const float*)d_in[2];
  const float* bng  = (const float*)d_in[3];
  const float* bnb  = (const float*)d_in[4];
  const float* bnm  = (const float*)d_in[5];
  const float* bnv  = (const float*)d_in[6];
  const float* lng  = (const float*)d_in[7];
  const float* lnb  = (const float*)d_in[8];
  const float* Win  = (const float*)d_in[9];
  const float* b_in = (const float*)d_in[10];
  const float* cw   = (const float*)d_in[11];
  const float* cb   = (const float*)d_in[12];
  const float* Wx   = (const float*)d_in[13];
  const float* Wdt  = (const float*)d_in[14];
  const float* bdt  = (const float*)d_in[15];
  const float* Alog = (const float*)d_in[16];
  const float* Dsk  = (const float*)d_in[17];
  const float* Wout = (const float*)d_in[18];
  const float* bout = (const float*)d_in[19];

  float* wsf = (float*)d_ws;
  float* v    = wsf;                     // 1204224
  float* xz   = v + 1204224;             // 4816896
  float* dtlb = xz + 4816896;            // 75264
  float* bcb  = dtlb + 75264;            // 200704
  float* Sb   = bcb + 200704;            // 2752512 (NC up to 224)
  float* Pb   = Sb + 2752512;            // dtsum: 172032 used; WdtT in tail
  __bf16* xiB = (__bf16*)(Pb + 2752512); // 2408448 bf16
  __bf16* yB  = (__bf16*)(Pb + 2752512 + 1204224);   // 2408448 bf16
  __bf16* Wb  = (__bf16*)(Pb + 2752512 + 2408448);   // 714240 bf16
  float* WdtT = Pb + 524288;             // 13824 fp32 (3 x 12 x 384)

  float* out0 = (float*)d_out;
  float* out1 = out0 + 301056;

  k_proj_wcvt<<<1006, 256, 0, stream>>>(x, pw, pb, bng, bnb, bnm, bnv, v,
                                        Win, Wout, Wx, Wb, Wdt, WdtT);

  for (int i = 0; i < 3; ++i) {
    const int big = (i < 2) ? 1 : 0;
    const int Lseq = big ? 3136 : 784;
    const int M = 2 * Lseq;
    const int NC = Lseq / SC_LC;     // 224 big, 56 small
    const int MB = (M + 63) / 64;    // 98 big, 25 small
    const int MB16 = M / 16;         // 392 big, 98 small
    const float* lng_i = lng + i * 192;
    const float* lnb_i = lnb + i * 192;
    const float* bin_i = b_in + i * 768;
    const float* cw_i  = cw + i * 384 * 4;
    const float* cb_i  = cb + i * 384;
    const float* WdtT_i = WdtT + i * 4608;
    const float* bdt_i = bdt + i * 384;
    const float* Al_i  = Alog + i * 384 * 16;
    const float* Ds_i  = Dsk + i * 384;
    const float* bo_i  = bout + i * 192;
    const __bf16* Winb_i  = Wb + i * 147456;
    const __bf16* Woutb_i = Wb + 442368 + i * 73728;
    const __bf16* Wxb_i   = Wb + 663552 + i * 16896;

    // xz = LN(src) @ Win^T + b_in  (streaming-W, 4 blk/CU)
    if (big)
      k_gemm_xz<2><<<dim3(MB, 6), 256, 0, stream>>>(
          v, Winb_i, bin_i, xz, M, lng_i, lnb_i);
    else
      k_gemm_xz<3><<<dim3(MB, 6), 256, 0, stream>>>(
          v, Winb_i, bin_i, xz, M, lng_i, lnb_i);
    // depthwise conv + silu -> xiB bf16
    k_conv<<<(M * 384 / 8 + 255) / 256, 256, 0, stream>>>(
        xz, xiB, cw_i, cb_i, Lseq, M * 384 / 8);
    // proj (44 cols): writes dtl (M x 12) + bc (M x 32); 16-row streaming blocks
    k_gemm_s<EPI_G2><<<dim3(MB16, 1), 256, 0, stream>>>(
        xiB, Wxb_i, nullptr, nullptr, M, 384, 44, dtlb, bcb, nullptr);
    k_scan1<<<dim3(2 * NC, 3), 256, 0, stream>>>(
        dtlb, xiB, bcb, WdtT_i, bdt_i, Al_i, Pb, Sb, Lseq, NC);
    k_carry<<<48, 256, 0, stream>>>(Pb, Sb, Al_i, NC);
    k_scan2<<<dim3(2 * NC, 3), 256, 0, stream>>>(
        dtlb, xiB, bcb, xz, WdtT_i, bdt_i, Al_i, Ds_i, Sb, yB, Lseq, NC);
    if (i == 0)
      k_gemm_s<EPI_RES><<<dim3(MB16, 3), 256, 0, stream>>>(
          yB, Woutb_i, bo_i, v, M, 384, 192, nullptr, nullptr, nullptr);
    else if (i == 1)
      k_gemm_s<EPI_RES_SKIP><<<dim3(MB16, 3), 256, 0, stream>>>(
          yB, Woutb_i, bo_i, v, M, 384, 192, nullptr, nullptr, out1);
    else
      k_gemm_s<EPI_OUT2><<<dim3(MB16, 3), 256, 0, stream>>>(
          yB, Woutb_i, bo_i, v, M, 384, 192, nullptr, nullptr, out0);
  }
}